// Round 1
// baseline (4100.243 us; speedup 1.0000x reference)
//
#include <hip/hip_runtime.h>
#include <math.h>

#define TLEN 32768
#define NFR  513
#define PI_F 3.14159265358979323846f

// float offsets in workspace
#define OFF_CW   0        // [65][128] window*cos
#define OFF_SW   8320     // [65][128] -window*sin
#define OFF_IC   16640    // [128][65] irfft cos coeff * w[k]/128 * cf
#define OFF_IS   24960    // [128][65] irfft -sin coeff
#define OFF_DEN  33280    // [64] 1/(w[k]^2+w[k+64]^2)
#define OFF_H    33344    // [8][256][513]
#define OFF_X    1083968  // [8][16][2][65][513]
#define OFF_Y    9620288  // [8][16][2][65][513]   (total 18,156,608 floats = 72.6 MB)

#define F4(p) (*reinterpret_cast<const float4*>(p))

__global__ void dfc_tables(float* __restrict__ ws) {
  int tid = threadIdx.x;
  for (int idx = tid; idx < 65*128; idx += 256) {
    int fb = idx >> 7, k = idx & 127;
    float wk = 0.5f*(1.0f - cosf(2.0f*PI_F*(float)k/128.0f));
    int ph = (fb*k) & 127;                      // exact mod-128 phase
    float ang = 2.0f*PI_F*(float)ph/128.0f;
    float cv = cosf(ang), sv = sinf(ang);
    ws[OFF_CW + idx] = wk*cv;
    ws[OFF_SW + idx] = -wk*sv;
    float cf = (fb == 0 || fb == 64) ? 1.0f : 2.0f;
    float sc = (1.0f/128.0f)*wk*cf;
    ws[OFF_IC + k*65 + fb] = sc*cv;
    ws[OFF_IS + k*65 + fb] = -sc*sv;
  }
  if (tid < 64) {
    float w0 = 0.5f*(1.0f - cosf(2.0f*PI_F*(float)tid/128.0f));
    float w1 = 0.5f*(1.0f - cosf(2.0f*PI_F*(float)(tid + 64)/128.0f));
    ws[OFF_DEN + tid] = 1.0f/fmaxf(w0*w0 + w1*w1, 1e-11f);
  }
}

// h[b,co,t] = b1[co] + sum_{ci,k} w1[co,ci,k]*cond[b,ci,64t+k-64]  (zero pad)
// block: 64 co x 32 t for one b; micro 4co x 2t
__launch_bounds__(256)
__global__ void dfc_conv1(const float* __restrict__ cond, const float* __restrict__ w1,
                          const float* __restrict__ b1, float* __restrict__ h) {
  __shared__ __align__(16) float seg[2176];     // XOR-swizzled time segment
  __shared__ __align__(16) float At[128*68];    // [k][co] XOR-swizzled
  const int b = blockIdx.z, co0 = blockIdx.y*64, t0 = blockIdx.x*32;
  const int tid = threadIdx.x;
  const int cop = (tid & 15)*4;
  const int tq  = (tid >> 4)*2;
  float acc[4][2] = {{0.f,0.f},{0.f,0.f},{0.f,0.f},{0.f,0.f}};
  const int gbase = t0*64 - 64;
  for (int ci = 0; ci < 128; ++ci) {
    __syncthreads();
    for (int j = tid; j < 2176; j += 256) {
      int g = gbase + j;
      float v = (g >= 0 && g < TLEN) ? cond[(b*128 + ci)*TLEN + g] : 0.0f;
      seg[j ^ (((j >> 6) & 7) << 2)] = v;
    }
    for (int idx = tid; idx < 8192; idx += 256) {
      int k = idx & 127, co = idx >> 7;
      At[k*68 + (co ^ ((k & 7) << 2))] = w1[((co0 + co)*128 + ci)*128 + k];
    }
    __syncthreads();
    #pragma unroll 2
    for (int k4 = 0; k4 < 32; ++k4) {
      float4 bv[2];
      #pragma unroll
      for (int u = 0; u < 2; ++u) {
        int j = (tq + u)*64 + k4*4;
        bv[u] = F4(&seg[j ^ (((j >> 6) & 7) << 2)]);
      }
      #pragma unroll
      for (int kk = 0; kk < 4; ++kk) {
        int k = k4*4 + kk;
        float4 av = F4(&At[k*68 + (cop ^ ((k & 7) << 2))]);
        float s0 = (kk == 0) ? bv[0].x : (kk == 1) ? bv[0].y : (kk == 2) ? bv[0].z : bv[0].w;
        float s1 = (kk == 0) ? bv[1].x : (kk == 1) ? bv[1].y : (kk == 2) ? bv[1].z : bv[1].w;
        acc[0][0] += av.x*s0; acc[0][1] += av.x*s1;
        acc[1][0] += av.y*s0; acc[1][1] += av.y*s1;
        acc[2][0] += av.z*s0; acc[2][1] += av.z*s1;
        acc[3][0] += av.w*s0; acc[3][1] += av.w*s1;
      }
    }
  }
  #pragma unroll
  for (int j = 0; j < 4; ++j) {
    int co = co0 + cop + j;
    float bb = b1[co];
    #pragma unroll
    for (int u = 0; u < 2; ++u) {
      int t = t0 + tq + u;
      if (t < NFR) h[(b*256 + co)*NFR + t] = acc[j][u] + bb;
    }
  }
}

// X[b,i,p,fb,t]: rfft of reflect-padded, windowed frames (window folded into tables)
__launch_bounds__(256)
__global__ void dfc_stft(const float* __restrict__ x, const float* __restrict__ ws,
                         float* __restrict__ X) {
  __shared__ __align__(16) float sfr[32*132];
  __shared__ __align__(16) float CWl[32*132];
  __shared__ __align__(16) float SWl[32*132];
  const int row = blockIdx.y, t0 = blockIdx.x*32, tid = threadIdx.x;
  for (int idx = tid; idx < 32*128; idx += 256) {
    int t = idx >> 7, k = idx & 127;
    int g = (t0 + t)*64 + k - 64;
    int s = (g < 0) ? -g : ((g >= TLEN) ? (2*TLEN - 2 - g) : g);
    sfr[t*132 + k] = x[row*TLEN + s];
  }
  const int fbl = tid >> 3, tg = tid & 7;
  for (int fbBase = 0; fbBase < 65; fbBase += 32) {
    const int nrows = (fbBase + 32 <= 65) ? 32 : (65 - fbBase);
    __syncthreads();
    for (int idx = tid; idx < nrows*128; idx += 256) {
      int r = idx >> 7, k = idx & 127;
      CWl[r*132 + k] = ws[OFF_CW + (fbBase + r)*128 + k];
      SWl[r*132 + k] = ws[OFF_SW + (fbBase + r)*128 + k];
    }
    __syncthreads();
    if (fbl < nrows) {
      float accR[4] = {0,0,0,0}, accI[4] = {0,0,0,0};
      #pragma unroll 4
      for (int k = 0; k < 128; ++k) {
        float cw = CWl[fbl*132 + k], sw = SWl[fbl*132 + k];
        #pragma unroll
        for (int u = 0; u < 4; ++u) {
          float sv = sfr[(tg + 8*u)*132 + k];
          accR[u] += sv*cw;
          accI[u] += sv*sw;
        }
      }
      const int fb = fbBase + fbl;
      #pragma unroll
      for (int u = 0; u < 4; ++u) {
        int t = t0 + tg + 8*u;
        if (t < NFR) {
          X[((row*2 + 0)*65 + fb)*NFR + t] = accR[u];
          X[((row*2 + 1)*65 + fb)*NFR + t] = accI[u];
        }
      }
    }
  }
}

// Fused conv2 + Y reduction, fb 0..63. Block: (b, o, 32 t); loops (p,i);
// f values live only in registers. micro: 2 fb x 4 t.
__launch_bounds__(256)
__global__ void dfc_conv2y(const float* __restrict__ h, const float* __restrict__ w2,
                           const float* __restrict__ b2, const float* __restrict__ X,
                           float* __restrict__ Y) {
  __shared__ __align__(16) float W2l[64*68];    // 64 fb rows x 64 c chunk, swizzled
  __shared__ __align__(16) float ht[32*260];    // [t][c]
  const int b = blockIdx.z, o = blockIdx.y, t0 = blockIdx.x*32;
  const int tid = threadIdx.x;
  const int fbg = tid >> 3, tg = tid & 7;       // fbg 0..31 (2 fb each), tg 0..7 (4 t each)
  for (int idx = tid; idx < 256*32; idx += 256) {
    int c = idx >> 5, t = idx & 31;
    ht[t*260 + c] = (t0 + t < NFR) ? h[(b*256 + c)*NFR + t0 + t] : 0.0f;
  }
  float yacc[2][2][4] = {};
  for (int pi = 0; pi < 32; ++pi) {
    const int p = pi >> 4, i = pi & 15;
    const int base = ((p*16 + o)*16 + i)*65;
    float facc[2][4] = {};
    for (int c0 = 0; c0 < 256; c0 += 64) {
      __syncthreads();
      for (int idx = tid; idx < 64*64; idx += 256) {
        int r = idx >> 6, cc = idx & 63;
        W2l[r*68 + (cc ^ (((r >> 1) & 7) << 2))] = w2[(base + r)*256 + c0 + cc];
      }
      __syncthreads();
      #pragma unroll 4
      for (int c4 = 0; c4 < 16; ++c4) {
        float4 hv[4];
        #pragma unroll
        for (int u = 0; u < 4; ++u)
          hv[u] = F4(&ht[(tg + 8*u)*260 + c0 + c4*4]);
        #pragma unroll
        for (int j = 0; j < 2; ++j) {
          int r = fbg*2 + j;
          float4 wr = F4(&W2l[r*68 + ((c4*4) ^ (((r >> 1) & 7) << 2))]);
          #pragma unroll
          for (int u = 0; u < 4; ++u)
            facc[j][u] += wr.x*hv[u].x + wr.y*hv[u].y + wr.z*hv[u].z + wr.w*hv[u].w;
        }
      }
    }
    #pragma unroll
    for (int j = 0; j < 2; ++j) {
      const int fb = fbg*2 + j;
      const float bb = b2[base + fb];
      #pragma unroll
      for (int u = 0; u < 4; ++u) {
        int t = t0 + tg + 8*u;
        float xv = X[(((b*16 + i)*2 + p)*65 + fb)*NFR + t]; // tail reads in-buffer garbage; writes guarded
        yacc[p][j][u] += (facc[j][u] + bb)*xv;
      }
    }
  }
  #pragma unroll
  for (int p = 0; p < 2; ++p)
    #pragma unroll
    for (int j = 0; j < 2; ++j) {
      const int fb = fbg*2 + j;
      #pragma unroll
      for (int u = 0; u < 4; ++u) {
        int t = t0 + tg + 8*u;
        if (t < NFR)
          Y[(((b*16 + o)*2 + p)*65 + fb)*NFR + t] = yacc[p][j][u];
      }
    }
}

// fb = 64 (Nyquist) slice of conv2+Y
__launch_bounds__(256)
__global__ void dfc_nyq(const float* __restrict__ h, const float* __restrict__ w2,
                        const float* __restrict__ b2, const float* __restrict__ X,
                        float* __restrict__ Y) {
  __shared__ __align__(16) float W2l[32*256];
  __shared__ float b2l[32];
  const int b = blockIdx.x, o = blockIdx.y, tid = threadIdx.x;
  for (int idx = tid; idx < 32*256; idx += 256) {
    int pi = idx >> 8, c = idx & 255;
    int p = pi >> 4, i = pi & 15;
    W2l[idx] = w2[(((p*16 + o)*16 + i)*65 + 64)*256 + c];
  }
  if (tid < 32) {
    int p = tid >> 4, i = tid & 15;
    b2l[tid] = b2[((p*16 + o)*16 + i)*65 + 64];
  }
  __syncthreads();
  for (int t = tid; t < NFR; t += 256) {
    float facc[32];
    #pragma unroll
    for (int pi = 0; pi < 32; ++pi) facc[pi] = 0.f;
    for (int c4 = 0; c4 < 64; ++c4) {
      float4 hv;
      hv.x = h[(b*256 + c4*4 + 0)*NFR + t];
      hv.y = h[(b*256 + c4*4 + 1)*NFR + t];
      hv.z = h[(b*256 + c4*4 + 2)*NFR + t];
      hv.w = h[(b*256 + c4*4 + 3)*NFR + t];
      #pragma unroll
      for (int pi = 0; pi < 32; ++pi) {
        float4 wv = F4(&W2l[pi*256 + c4*4]);
        facc[pi] += wv.x*hv.x + wv.y*hv.y + wv.z*hv.z + wv.w*hv.w;
      }
    }
    float y0 = 0.f, y1 = 0.f;
    #pragma unroll
    for (int pi = 0; pi < 32; ++pi) {
      int p = pi >> 4, i = pi & 15;
      float f = facc[pi] + b2l[pi];
      float xv = X[(((b*16 + i)*2 + p)*65 + 64)*NFR + t];
      if (p == 0) y0 += f*xv; else y1 += f*xv;
    }
    Y[(((b*16 + o)*2 + 0)*65 + 64)*NFR + t] = y0;
    Y[(((b*16 + o)*2 + 1)*65 + 64)*NFR + t] = y1;
  }
}

// iSTFT: out[row,s] = (fr[u][k1+64] + fr[u+1][k1]) * invden[k1] + bias
// fr[t][k] = sum_fb IC[k][fb]*Yr[t][fb] + IS[k][fb]*Yi[t][fb]   (window folded in)
__launch_bounds__(256)
__global__ void dfc_istft(const float* __restrict__ Y, const float* __restrict__ ws,
                          const float* __restrict__ bias, float* __restrict__ out) {
  __shared__ __align__(16) float Tc[128*36];
  __shared__ __align__(16) float Ts[128*36];
  __shared__ __align__(16) float Yl[2*17*68];   // [p][tloc][fb]
  __shared__ float invden[64];
  const int row = blockIdx.y, u0 = blockIdx.x*16, tid = threadIdx.x;
  for (int idx = tid; idx < 2*65*17; idx += 256) {
    int pfb = idx/17, tl = idx - pfb*17;
    int p = (pfb >= 65) ? 1 : 0;
    int fb = pfb - p*65;
    Yl[(p*17 + tl)*68 + fb] = Y[((row*2 + p)*65 + fb)*NFR + u0 + tl];
  }
  if (tid < 64) invden[tid] = ws[OFF_DEN + tid];
  const int k1 = tid & 63, uu = tid >> 6;
  const int kA = k1 + 64, kB = k1;
  float acc[4] = {0,0,0,0};
  for (int half = 0; half < 2; ++half) {
    const int fb0 = half*32, ncol = half ? 33 : 32;
    __syncthreads();
    for (int idx = tid; idx < 128*ncol; idx += 256) {
      int k = idx/ncol, fb = idx - k*ncol;
      Tc[k*36 + fb] = ws[OFF_IC + k*65 + fb0 + fb];
      Ts[k*36 + fb] = ws[OFF_IS + k*65 + fb0 + fb];
    }
    __syncthreads();
    #pragma unroll
    for (int it = 0; it < 4; ++it) {
      const int u = it*4 + uu;
      const int tA = u, tB = u + 1;
      float a = 0.f;
      #pragma unroll 2
      for (int f4 = 0; f4 < 8; ++f4) {
        float4 icA = F4(&Tc[kA*36 + f4*4]);
        float4 isA = F4(&Ts[kA*36 + f4*4]);
        float4 icB = F4(&Tc[kB*36 + f4*4]);
        float4 isB = F4(&Ts[kB*36 + f4*4]);
        float4 yrA = F4(&Yl[(0*17 + tA)*68 + fb0 + f4*4]);
        float4 yiA = F4(&Yl[(1*17 + tA)*68 + fb0 + f4*4]);
        float4 yrB = F4(&Yl[(0*17 + tB)*68 + fb0 + f4*4]);
        float4 yiB = F4(&Yl[(1*17 + tB)*68 + fb0 + f4*4]);
        a += icA.x*yrA.x + icA.y*yrA.y + icA.z*yrA.z + icA.w*yrA.w;
        a += isA.x*yiA.x + isA.y*yiA.y + isA.z*yiA.z + isA.w*yiA.w;
        a += icB.x*yrB.x + icB.y*yrB.y + icB.z*yrB.z + icB.w*yrB.w;
        a += isB.x*yiB.x + isB.y*yiB.y + isB.z*yiB.z + isB.w*yiB.w;
      }
      if (half == 1) {
        a += Tc[kA*36 + 32]*Yl[(0*17 + tA)*68 + 64] + Ts[kA*36 + 32]*Yl[(1*17 + tA)*68 + 64];
        a += Tc[kB*36 + 32]*Yl[(0*17 + tB)*68 + 64] + Ts[kB*36 + 32]*Yl[(1*17 + tB)*68 + 64];
      }
      acc[it] += a;
    }
  }
  const float bv = bias[row & 15];
  #pragma unroll
  for (int it = 0; it < 4; ++it) {
    int s = it*256 + tid;
    out[row*TLEN + u0*64 + s] = acc[it]*invden[k1] + bv;
  }
}

extern "C" void kernel_launch(void* const* d_in, const int* in_sizes, int n_in,
                              void* d_out, int out_size, void* d_ws, size_t ws_size,
                              hipStream_t stream) {
  (void)in_sizes; (void)n_in; (void)out_size; (void)ws_size;
  const float* x    = (const float*)d_in[0];
  const float* cond = (const float*)d_in[1];
  const float* w1   = (const float*)d_in[2];
  const float* b1   = (const float*)d_in[3];
  const float* w2   = (const float*)d_in[4];
  const float* b2   = (const float*)d_in[5];
  const float* bias = (const float*)d_in[6];
  float* ws  = (float*)d_ws;
  float* out = (float*)d_out;
  float* h  = ws + OFF_H;
  float* Xb = ws + OFF_X;
  float* Yb = ws + OFF_Y;
  dfc_tables<<<dim3(1), dim3(256), 0, stream>>>(ws);
  dfc_conv1<<<dim3(17, 4, 8), dim3(256), 0, stream>>>(cond, w1, b1, h);
  dfc_stft<<<dim3(17, 128), dim3(256), 0, stream>>>(x, ws, Xb);
  dfc_conv2y<<<dim3(17, 16, 8), dim3(256), 0, stream>>>(h, w2, b2, Xb, Yb);
  dfc_nyq<<<dim3(8, 16), dim3(256), 0, stream>>>(h, w2, b2, Xb, Yb);
  dfc_istft<<<dim3(32, 128), dim3(256), 0, stream>>>(Yb, ws, bias, out);
}

// Round 2
// 691.157 us; speedup vs baseline: 5.9324x; 5.9324x over previous
//
#include <hip/hip_runtime.h>
#include <math.h>

#define TLEN 32768
#define NFR  513
#define TP   576          // padded frame count (multiple of 96 and 64)
#define FP   68           // padded freq count (65 -> 68, keeps 8B alignment)
#define PI_F 3.14159265358979323846f

typedef unsigned short u16;
typedef unsigned int   u32;
typedef _Float16 h16;
typedef h16  half8  __attribute__((ext_vector_type(8)));
typedef h16  half4  __attribute__((ext_vector_type(4)));
typedef h16  half2v __attribute__((ext_vector_type(2)));
typedef float f32x4 __attribute__((ext_vector_type(4)));

// float-unit offsets in workspace
#define OFF_CW   0        // [65][128] window*cos
#define OFF_SW   8320     // [65][128] -window*sin
#define OFF_IC   16640    // [128][65] irfft cos * w/128 * cf
#define OFF_IS   24960    // [128][65]
#define OFF_DEN  33280    // [64]
#define OFF_R    33344    // region R: hpart fp16 [8][8][513][256] THEN w216 fp16 [33280][256]
#define OFF_HT   4293184  // hT16 fp16 [8][576][256], row-swizzled
#define OFF_X16  4883008  // X16 fp16 [8*16][2][576][68]
#define OFF_Y16  9896512  // Y16 fp16 [8*16][2][513][68]
#define OFF_W116 14361664 // w116 fp16 [128ci][256co][128k]
// end: 16,458,816 floats = 65.8 MB (< round-1's 72.6 MB footprint)

#define F4(p) (*reinterpret_cast<const float4*>(p))
#define GLDS(gsrc, ldst) __builtin_amdgcn_global_load_lds( \
    (const __attribute__((address_space(1))) void*)(gsrc),  \
    (__attribute__((address_space(3))) void*)(ldst), 16, 0, 0)

__device__ __forceinline__ u16 pkh(float v) { return __builtin_bit_cast(u16, (h16)v); }

__global__ void dfc_tables(float* __restrict__ ws) {
  int tid = threadIdx.x;
  for (int idx = tid; idx < 65*128; idx += 256) {
    int fb = idx >> 7, k = idx & 127;
    float wk = 0.5f*(1.0f - cosf(2.0f*PI_F*(float)k/128.0f));
    int ph = (fb*k) & 127;
    float ang = 2.0f*PI_F*(float)ph/128.0f;
    float cv = cosf(ang), sv = sinf(ang);
    ws[OFF_CW + idx] = wk*cv;
    ws[OFF_SW + idx] = -wk*sv;
    float cf = (fb == 0 || fb == 64) ? 1.0f : 2.0f;
    float sc = (1.0f/128.0f)*wk*cf;
    ws[OFF_IC + k*65 + fb] = sc*cv;
    ws[OFF_IS + k*65 + fb] = -sc*sv;
  }
  if (tid < 64) {
    float w0 = 0.5f*(1.0f - cosf(2.0f*PI_F*(float)tid/128.0f));
    float w1 = 0.5f*(1.0f - cosf(2.0f*PI_F*(float)(tid + 64)/128.0f));
    ws[OFF_DEN + tid] = 1.0f/fmaxf(w0*w0 + w1*w1, 1e-11f);
  }
}

// w116[ci][co][k] = fp16(w1[co][ci][k])  (plain, A-frags read direct from global)
__launch_bounds__(256)
__global__ void dfc_prep_w1(const float* __restrict__ w1, u16* __restrict__ w116) {
  int idx = blockIdx.x*256 + threadIdx.x;           // < 524288
  int k8 = idx & 15, rc = idx >> 4;
  int co = rc & 255, ci = rc >> 8;
  const float* src = w1 + ((size_t)(co*128 + ci)*128 + k8*8);
  float4 a = F4(src), b = F4(src + 4);
  half8 hv;
  hv[0]=(h16)a.x; hv[1]=(h16)a.y; hv[2]=(h16)a.z; hv[3]=(h16)a.w;
  hv[4]=(h16)b.x; hv[5]=(h16)b.y; hv[6]=(h16)b.z; hv[7]=(h16)b.w;
  *(half8*)((h16*)w116 + (size_t)idx*8) = hv;
}

// w216[row][c] = fp16(w2[row][c]) with in-row chunk swizzle: chunk c/8 ^ (fb&7), fb=row%65
__launch_bounds__(256)
__global__ void dfc_prep_w2(const float* __restrict__ w2, u16* __restrict__ w216) {
  int idx = blockIdx.x*256 + threadIdx.x;           // < 1064960
  int cc = idx & 31, r = idx >> 5;
  int fb = r % 65;
  const float* src = w2 + (size_t)r*256 + cc*8;
  float4 a = F4(src), b = F4(src + 4);
  half8 hv;
  hv[0]=(h16)a.x; hv[1]=(h16)a.y; hv[2]=(h16)a.z; hv[3]=(h16)a.w;
  hv[4]=(h16)b.x; hv[5]=(h16)b.y; hv[6]=(h16)b.z; hv[7]=(h16)b.w;
  *(half8*)((h16*)w216 + (size_t)r*256 + ((cc ^ (fb & 7)) << 3)) = hv;
}

// conv1 via MFMA: hpart[kc][b][t][co] (fp16) partial over 16 ci
__launch_bounds__(256, 2)
__global__ void dfc_conv1(const float* __restrict__ cond, const u16* __restrict__ w116,
                          u16* __restrict__ hpart) {
  __shared__ u32 segu[2112];                         // 4224 fp16 samples, addr-XOR swizzled
  const int t0 = blockIdx.x * 64;
  const int b  = blockIdx.y;
  const int kc = blockIdx.z;
  const int tid = threadIdx.x;
  const int wave = tid >> 6, lane = tid & 63;
  const int l15 = lane & 15, g16 = lane >> 4;
  f32x4 acc[4][4] = {};                              // [mi][nt]
  const int gbase = t0*64 - 64;
  const h16* w116h = (const h16*)w116;
  for (int cl = 0; cl < 16; ++cl) {
    const int ci = kc*16 + cl;
    __syncthreads();
    const float* cb = cond + (size_t)(b*128 + ci)*TLEN;
    for (int s2 = tid; s2 < 2112; s2 += 256) {
      int g0 = gbase + 2*s2;
      float a0 = (g0 >= 0 && g0 < TLEN) ? cb[g0] : 0.0f;
      float a1 = (g0+1 >= 0 && g0+1 < TLEN) ? cb[g0+1] : 0.0f;
      u32 u = (u32)pkh(a0) | ((u32)pkh(a1) << 16);
      segu[s2 ^ (((s2 >> 5) & 7) << 2)] = u;
    }
    __syncthreads();
    const h16* wb = w116h + (size_t)ci*32768;
    #pragma unroll
    for (int ks = 0; ks < 4; ++ks) {
      half8 Bf[4];
      #pragma unroll
      for (int nt = 0; nt < 4; ++nt) {
        int byte = 128*(nt*16 + l15) + 64*ks + 16*g16;
        byte ^= ((byte >> 7) & 7) << 4;
        Bf[nt] = *(const half8*)((const char*)segu + byte);
      }
      #pragma unroll
      for (int mi = 0; mi < 4; ++mi) {
        int co = (wave*4 + mi)*16 + l15;
        half8 Af = *(const half8*)(wb + co*128 + ks*32 + g16*8);
        #pragma unroll
        for (int nt = 0; nt < 4; ++nt)
          acc[mi][nt] = __builtin_amdgcn_mfma_f32_16x16x32_f16(Af, Bf[nt], acc[mi][nt], 0,0,0);
      }
    }
  }
  h16* hp = (h16*)hpart;
  #pragma unroll
  for (int mi = 0; mi < 4; ++mi) {
    const int co0 = (wave*4 + mi)*16 + g16*4;
    #pragma unroll
    for (int nt = 0; nt < 4; ++nt) {
      int t = t0 + nt*16 + l15;
      if (t < NFR) {
        half4 v;
        v[0]=(h16)acc[mi][nt][0]; v[1]=(h16)acc[mi][nt][1];
        v[2]=(h16)acc[mi][nt][2]; v[3]=(h16)acc[mi][nt][3];
        *(half4*)(hp + ((size_t)(kc*8 + b)*NFR + t)*256 + co0) = v;
      }
    }
  }
}

// reduce 8 partials + b1 -> hT16[b][t][c] fp16, chunk-swizzled (c/8 ^ (t&7))
__launch_bounds__(256)
__global__ void dfc_hred(const u16* __restrict__ hpart, const float* __restrict__ b1,
                         u16* __restrict__ hT16) {
  int idx = blockIdx.x*256 + threadIdx.x;            // < 131328 = 8*513*32
  int b = idx / 16416, r = idx % 16416;
  int t = r >> 5, cc = r & 31;
  float s[8];
  float4 ba = F4(&b1[cc*8]), bb = F4(&b1[cc*8 + 4]);
  s[0]=ba.x; s[1]=ba.y; s[2]=ba.z; s[3]=ba.w; s[4]=bb.x; s[5]=bb.y; s[6]=bb.z; s[7]=bb.w;
  const h16* hp = (const h16*)hpart;
  #pragma unroll
  for (int kc = 0; kc < 8; ++kc) {
    half8 hv = *(const half8*)(hp + ((size_t)(kc*8 + b)*NFR + t)*256 + cc*8);
    #pragma unroll
    for (int j = 0; j < 8; ++j) s[j] += (float)hv[j];
  }
  half8 o;
  #pragma unroll
  for (int j = 0; j < 8; ++j) o[j] = (h16)s[j];
  *(half8*)((h16*)hT16 + ((size_t)b*TP + t)*256 + ((cc ^ (t & 7)) << 3)) = o;
}

// STFT -> X16 fp16 [row][p][t(TP)][fb(FP)]
__launch_bounds__(256)
__global__ void dfc_stft(const float* __restrict__ x, const float* __restrict__ wsp,
                         u16* __restrict__ X16) {
  __shared__ __align__(16) float sfr[32*132];
  __shared__ __align__(16) float CWl[32*132];
  __shared__ __align__(16) float SWl[32*132];
  __shared__ __align__(16) u16 Xt[32*136];           // [t][p*68+fb]
  const int row = blockIdx.y, t0 = blockIdx.x*32, tid = threadIdx.x;
  for (int idx = tid; idx < 32*128; idx += 256) {
    int t = idx >> 7, k = idx & 127;
    int g = (t0 + t)*64 + k - 64;
    int s = (g < 0) ? -g : ((g >= TLEN) ? (2*TLEN - 2 - g) : g);
    sfr[t*132 + k] = x[(size_t)row*TLEN + s];
  }
  const int fbl = tid >> 3, tg = tid & 7;
  float aR[3][4], aI[3][4];
  for (int ps = 0; ps < 3; ++ps) {
    const int fbBase = ps*32;
    const int nrows = (fbBase + 32 <= 65) ? 32 : (65 - fbBase);
    __syncthreads();
    for (int idx = tid; idx < nrows*128; idx += 256) {
      int r = idx >> 7, k = idx & 127;
      CWl[r*132 + k] = wsp[OFF_CW + (fbBase + r)*128 + k];
      SWl[r*132 + k] = wsp[OFF_SW + (fbBase + r)*128 + k];
    }
    __syncthreads();
    #pragma unroll
    for (int u = 0; u < 4; ++u) { aR[ps][u] = 0.f; aI[ps][u] = 0.f; }
    if (fbl < nrows) {
      #pragma unroll 4
      for (int k = 0; k < 128; ++k) {
        float cw = CWl[fbl*132 + k], sw = SWl[fbl*132 + k];
        #pragma unroll
        for (int u = 0; u < 4; ++u) {
          float sv = sfr[(tg + 8*u)*132 + k];
          aR[ps][u] += sv*cw;
          aI[ps][u] += sv*sw;
        }
      }
    }
  }
  __syncthreads();
  #pragma unroll
  for (int ps = 0; ps < 3; ++ps) {
    const int fb = ps*32 + fbl;
    if (fb <= 64) {
      #pragma unroll
      for (int u = 0; u < 4; ++u) {
        int tl = tg + 8*u;
        Xt[tl*136 + fb]      = pkh(aR[ps][u]);
        Xt[tl*136 + 68 + fb] = pkh(aI[ps][u]);
      }
    }
  }
  __syncthreads();
  const u32* Xtw = (const u32*)Xt;
  for (int idx = tid; idx < 2176; idx += 256) {      // 64 rows * 34 dwords
    int tp = idx / 34, dw = idx - tp*34;
    int tl = tp >> 1, p = tp & 1;
    int t = t0 + tl;
    if (t < NFR) {
      u32* dst = (u32*)((h16*)X16 + ((size_t)(row*2 + p)*TP + t)*FP);
      dst[dw] = Xtw[tl*68 + p*34 + dw];
    }
  }
}

// Fused conv2 + X-mul + i-reduction via MFMA. Block: (96-t-tile, o, b).
// M=128 rows=(p,fb0..63), K=256 (4 chunks of 64), loop i=0..15.
__launch_bounds__(256, 2)
__global__ void dfc_conv2y(const u16* __restrict__ w216, const u16* __restrict__ hT16,
                           const float* __restrict__ b2, const u16* __restrict__ X16,
                           u16* __restrict__ Y16) {
  __shared__ __align__(16) char Al[16384];           // [128 rows][128 B]
  __shared__ __align__(16) char Bl[12288];           // [96 t][128 B]
  __shared__ float b2l[2048];                        // [p][i][fb]
  const int t0 = blockIdx.x * 96;
  const int o  = blockIdx.y;
  const int b  = blockIdx.z;
  const int tid = threadIdx.x;
  const int wave = tid >> 6, lane = tid & 63;
  const int wp = wave >> 1, wn = wave & 1;
  const int l15 = lane & 15, g16 = lane >> 4;
  const int lrow8 = lane >> 3, lcol = (lane & 7) * 16;

  for (int idx = tid; idx < 2048; idx += 256) {
    int p = idx >> 10, r = idx & 1023, i = r >> 6, fb = r & 63;
    b2l[idx] = b2[(size_t)((p*16 + o)*16 + i)*65 + fb];
  }

  const char* wb = (const char*)w216;
  const char* hb = (const char*)hT16;
  f32x4 yac[4][3] = {};
  for (int i = 0; i < 16; ++i) {
    const int rb0 = (o*16 + i)*65;
    const int rb1 = (256 + o*16 + i)*65;
    f32x4 fac[4][3];
    #pragma unroll
    for (int mi = 0; mi < 4; ++mi) {
      int fb0 = mi*16 + g16*4;
      float bv0 = b2l[(wp*16 + i)*64 + fb0];
      float bv1 = b2l[(wp*16 + i)*64 + fb0 + 1];
      float bv2 = b2l[(wp*16 + i)*64 + fb0 + 2];
      float bv3 = b2l[(wp*16 + i)*64 + fb0 + 3];
      #pragma unroll
      for (int nt = 0; nt < 3; ++nt) { fac[mi][nt][0]=bv0; fac[mi][nt][1]=bv1; fac[mi][nt][2]=bv2; fac[mi][nt][3]=bv3; }
    }
    for (int kk = 0; kk < 4; ++kk) {
      __syncthreads();
      #pragma unroll
      for (int j = 0; j < 4; ++j) {                  // A: 16 KB
        int r = wave*32 + j*8 + lrow8;
        int wrow = (r < 64) ? (rb0 + r) : (rb1 + (r - 64));
        GLDS(wb + (((size_t)wrow*256 + kk*64) << 1) + lcol, Al + (wave*32 + j*8)*128);
      }
      #pragma unroll
      for (int j = 0; j < 3; ++j) {                  // B: 12 KB
        int tr = wave*24 + j*8 + lrow8;
        GLDS(hb + ((((size_t)b*TP + t0 + tr)*256 + kk*64) << 1) + lcol, Bl + (wave*24 + j*8)*128);
      }
      __syncthreads();
      #pragma unroll
      for (int ks = 0; ks < 2; ++ks) {
        half8 Af[4], Bf[3];
        #pragma unroll
        for (int mi = 0; mi < 4; ++mi) {
          int r = wp*64 + mi*16 + l15;
          int byte = r*128 + ks*64 + g16*16;
          byte ^= (r & 7) << 4;
          Af[mi] = *(const half8*)(Al + byte);
        }
        #pragma unroll
        for (int nt = 0; nt < 3; ++nt) {
          int tr = wn*48 + nt*16 + l15;
          int byte = tr*128 + ks*64 + g16*16;
          byte ^= (tr & 7) << 4;
          Bf[nt] = *(const half8*)(Bl + byte);
        }
        #pragma unroll
        for (int mi = 0; mi < 4; ++mi)
          #pragma unroll
          for (int nt = 0; nt < 3; ++nt)
            fac[mi][nt] = __builtin_amdgcn_mfma_f32_16x16x32_f16(Af[mi], Bf[nt], fac[mi][nt], 0,0,0);
      }
    }
    // epilogue: yac += fac * X
    const h16* Xrow = (const h16*)X16 + (size_t)((b*16 + i)*2 + wp)*TP*FP;
    #pragma unroll
    for (int mi = 0; mi < 4; ++mi) {
      int fb0 = mi*16 + g16*4;
      #pragma unroll
      for (int nt = 0; nt < 3; ++nt) {
        int t = t0 + wn*48 + nt*16 + l15;
        half4 xv = *(const half4*)(Xrow + (size_t)t*FP + fb0);
        yac[mi][nt][0] += fac[mi][nt][0] * (float)xv[0];
        yac[mi][nt][1] += fac[mi][nt][1] * (float)xv[1];
        yac[mi][nt][2] += fac[mi][nt][2] * (float)xv[2];
        yac[mi][nt][3] += fac[mi][nt][3] * (float)xv[3];
      }
    }
  }
  h16* Yh = (h16*)Y16;
  const int orow = (b*16 + o)*2 + wp;
  #pragma unroll
  for (int mi = 0; mi < 4; ++mi) {
    int fb0 = mi*16 + g16*4;
    #pragma unroll
    for (int nt = 0; nt < 3; ++nt) {
      int t = t0 + wn*48 + nt*16 + l15;
      if (t < NFR) {
        half4 v;
        v[0]=(h16)yac[mi][nt][0]; v[1]=(h16)yac[mi][nt][1];
        v[2]=(h16)yac[mi][nt][2]; v[3]=(h16)yac[mi][nt][3];
        *(half4*)(Yh + ((size_t)orow*NFR + t)*FP + fb0) = v;
      }
    }
  }
}

// fb=64 (Nyquist) slice: f32 dots over contiguous fp16 h rows
__launch_bounds__(256)
__global__ void dfc_edge(const float* __restrict__ w2, const float* __restrict__ b2,
                         const u16* __restrict__ hT16, const u16* __restrict__ X16,
                         u16* __restrict__ Y16) {
  __shared__ float Wl[8192];                         // [pi 32][c 256]
  __shared__ float b2l[32];
  const int o = blockIdx.x, b = blockIdx.y, tid = threadIdx.x;
  for (int idx = tid; idx < 8192; idx += 256) {
    int pi = idx >> 8, c = idx & 255;
    int p = pi >> 4, i = pi & 15;
    Wl[idx] = w2[(size_t)(((p*16 + o)*16 + i)*65 + 64)*256 + c];
  }
  if (tid < 32) {
    int p = tid >> 4, i = tid & 15;
    b2l[tid] = b2[(size_t)((p*16 + o)*16 + i)*65 + 64];
  }
  __syncthreads();
  const h16* hh = (const h16*)hT16;
  const h16* Xh = (const h16*)X16;
  h16* Yh = (h16*)Y16;
  for (int t = tid; t < NFR; t += 256) {
    int key = t & 7;
    float facc[32];
    #pragma unroll
    for (int pi = 0; pi < 32; ++pi) facc[pi] = b2l[pi];
    const h16* hrow = hh + ((size_t)b*TP + t)*256;
    for (int cc = 0; cc < 32; ++cc) {
      half8 hv = *(const half8*)(hrow + ((cc ^ key) << 3));
      float h0=(float)hv[0], h1=(float)hv[1], h2=(float)hv[2], h3=(float)hv[3];
      float h4=(float)hv[4], h5=(float)hv[5], h6=(float)hv[6], h7=(float)hv[7];
      #pragma unroll
      for (int pi = 0; pi < 32; ++pi) {
        const float* wr = &Wl[pi*256 + cc*8];
        facc[pi] += wr[0]*h0 + wr[1]*h1 + wr[2]*h2 + wr[3]*h3
                  + wr[4]*h4 + wr[5]*h5 + wr[6]*h6 + wr[7]*h7;
      }
    }
    float y0 = 0.f, y1 = 0.f;
    #pragma unroll
    for (int pi = 0; pi < 32; ++pi) {
      int p = pi >> 4, i = pi & 15;
      float xv = (float)Xh[((size_t)((b*16 + i)*2 + p)*TP + t)*FP + 64];
      if (p == 0) y0 += facc[pi]*xv; else y1 += facc[pi]*xv;
    }
    Yh[((size_t)((b*16 + o)*2 + 0)*NFR + t)*FP + 64] = (h16)y0;
    Yh[((size_t)((b*16 + o)*2 + 1)*NFR + t)*FP + 64] = (h16)y1;
  }
}

// iSTFT from Y16 fp16
__launch_bounds__(256)
__global__ void dfc_istft(const u16* __restrict__ Y16, const float* __restrict__ wsp,
                          const float* __restrict__ bias, float* __restrict__ out) {
  __shared__ __align__(16) float Tc[128*36];
  __shared__ __align__(16) float Ts[128*36];
  __shared__ __align__(16) float Yl[2*17*68];
  __shared__ float invden[64];
  const int row = blockIdx.y, u0 = blockIdx.x*16, tid = threadIdx.x;
  const h16* Yh = (const h16*)Y16;
  for (int q = tid; q < 1156; q += 256) {            // 2p * 17t * 34 pairs
    int p = q / 578, r = q - p*578, tl = r / 34, fbp = r - tl*34;
    half2v v = *(const half2v*)(Yh + ((size_t)(row*2 + p)*NFR + u0 + tl)*FP + fbp*2);
    Yl[(p*17 + tl)*68 + fbp*2]     = (float)v[0];
    Yl[(p*17 + tl)*68 + fbp*2 + 1] = (float)v[1];
  }
  if (tid < 64) invden[tid] = wsp[OFF_DEN + tid];
  const int k1 = tid & 63, uu = tid >> 6;
  const int kA = k1 + 64, kB = k1;
  float acc[4] = {0,0,0,0};
  for (int half = 0; half < 2; ++half) {
    const int fb0 = half*32, ncol = half ? 33 : 32;
    __syncthreads();
    for (int idx = tid; idx < 128*ncol; idx += 256) {
      int k = idx/ncol, fb = idx - k*ncol;
      Tc[k*36 + fb] = wsp[OFF_IC + k*65 + fb0 + fb];
      Ts[k*36 + fb] = wsp[OFF_IS + k*65 + fb0 + fb];
    }
    __syncthreads();
    #pragma unroll
    for (int it = 0; it < 4; ++it) {
      const int u = it*4 + uu;
      const int tA = u, tB = u + 1;
      float a = 0.f;
      #pragma unroll 2
      for (int f4 = 0; f4 < 8; ++f4) {
        float4 icA = F4(&Tc[kA*36 + f4*4]);
        float4 isA = F4(&Ts[kA*36 + f4*4]);
        float4 icB = F4(&Tc[kB*36 + f4*4]);
        float4 isB = F4(&Ts[kB*36 + f4*4]);
        float4 yrA = F4(&Yl[(0*17 + tA)*68 + fb0 + f4*4]);
        float4 yiA = F4(&Yl[(1*17 + tA)*68 + fb0 + f4*4]);
        float4 yrB = F4(&Yl[(0*17 + tB)*68 + fb0 + f4*4]);
        float4 yiB = F4(&Yl[(1*17 + tB)*68 + fb0 + f4*4]);
        a += icA.x*yrA.x + icA.y*yrA.y + icA.z*yrA.z + icA.w*yrA.w;
        a += isA.x*yiA.x + isA.y*yiA.y + isA.z*yiA.z + isA.w*yiA.w;
        a += icB.x*yrB.x + icB.y*yrB.y + icB.z*yrB.z + icB.w*yrB.w;
        a += isB.x*yiB.x + isB.y*yiB.y + isB.z*yiB.z + isB.w*yiB.w;
      }
      if (half == 1) {
        a += Tc[kA*36 + 32]*Yl[(0*17 + tA)*68 + 64] + Ts[kA*36 + 32]*Yl[(1*17 + tA)*68 + 64];
        a += Tc[kB*36 + 32]*Yl[(0*17 + tB)*68 + 64] + Ts[kB*36 + 32]*Yl[(1*17 + tB)*68 + 64];
      }
      acc[it] += a;
    }
  }
  const float bv = bias[row & 15];
  #pragma unroll
  for (int it = 0; it < 4; ++it) {
    int s = it*256 + tid;
    out[(size_t)row*TLEN + u0*64 + s] = acc[it]*invden[k1] + bv;
  }
}

extern "C" void kernel_launch(void* const* d_in, const int* in_sizes, int n_in,
                              void* d_out, int out_size, void* d_ws, size_t ws_size,
                              hipStream_t stream) {
  (void)in_sizes; (void)n_in; (void)out_size; (void)ws_size;
  const float* x    = (const float*)d_in[0];
  const float* cond = (const float*)d_in[1];
  const float* w1   = (const float*)d_in[2];
  const float* b1   = (const float*)d_in[3];
  const float* w2   = (const float*)d_in[4];
  const float* b2   = (const float*)d_in[5];
  const float* bias = (const float*)d_in[6];
  float* ws  = (float*)d_ws;
  float* out = (float*)d_out;
  u16* R     = (u16*)(ws + OFF_R);      // hpart then w216
  u16* hT16  = (u16*)(ws + OFF_HT);
  u16* X16   = (u16*)(ws + OFF_X16);
  u16* Y16   = (u16*)(ws + OFF_Y16);
  u16* w116  = (u16*)(ws + OFF_W116);

  hipMemsetAsync(hT16, 0, (size_t)8*TP*256*2, stream);
  hipMemsetAsync(X16, 0, (size_t)256*TP*FP*2, stream);
  dfc_tables<<<dim3(1), dim3(256), 0, stream>>>(ws);
  dfc_prep_w1<<<dim3(2048), dim3(256), 0, stream>>>(w1, w116);
  dfc_conv1<<<dim3(9, 8, 8), dim3(256), 0, stream>>>(cond, w116, R);
  dfc_hred<<<dim3(513), dim3(256), 0, stream>>>(R, b1, hT16);
  dfc_prep_w2<<<dim3(4160), dim3(256), 0, stream>>>(w2, R);
  dfc_stft<<<dim3(17, 128), dim3(256), 0, stream>>>(x, ws, X16);
  dfc_conv2y<<<dim3(6, 16, 8), dim3(256), 0, stream>>>(R, hT16, b2, X16, Y16);
  dfc_edge<<<dim3(16, 8), dim3(256), 0, stream>>>(w2, b2, hT16, X16, Y16);
  dfc_istft<<<dim3(32, 128), dim3(256), 0, stream>>>(Y16, ws, bias, out);
}

// Round 3
// 626.290 us; speedup vs baseline: 6.5469x; 1.1036x over previous
//
#include <hip/hip_runtime.h>
#include <math.h>

#define TLEN 32768
#define NFR  513
#define TP   576          // padded frame count
#define FP   68           // padded freq count
#define PI_F 3.14159265358979323846f

typedef unsigned short u16;
typedef unsigned int   u32;
typedef _Float16 h16;
typedef h16  half8  __attribute__((ext_vector_type(8)));
typedef h16  half4  __attribute__((ext_vector_type(4)));
typedef h16  half2v __attribute__((ext_vector_type(2)));
typedef float f32x4 __attribute__((ext_vector_type(4)));

// float-unit offsets in workspace
#define OFF_CW   0        // [65][128] window*cos
#define OFF_SW   8320     // [65][128] -window*sin
#define OFF_IC   16640    // [128][65] irfft cos * w/128 * cf
#define OFF_IS   24960    // [128][65]
#define OFF_DEN  33280    // [64]
#define OFF_R    33344    // region R: hpart fp16 [8][8][513][256] THEN w216 fp16 [33280][256]
#define OFF_HT   4293184  // hT16 fp16 [8][576][256], row-swizzled
#define OFF_X16  4883008  // X16 fp16 [8*16][2][576][68]
#define OFF_Y16  9896512  // Y16 fp16 [8*16][2][513][68]
#define OFF_W116 14361664 // w116 fp16 [128ci][256co][128k]
// end: 16,458,816 floats = 65.8 MB

#define F4(p) (*reinterpret_cast<const float4*>(p))
#define GLDS(gsrc, ldst) __builtin_amdgcn_global_load_lds( \
    (const __attribute__((address_space(1))) void*)(gsrc),  \
    (__attribute__((address_space(3))) void*)(ldst), 16, 0, 0)

__device__ __forceinline__ u16 pkh(float v) { return __builtin_bit_cast(u16, (h16)v); }

__global__ void dfc_tables(float* __restrict__ ws) {
  int tid = threadIdx.x;
  for (int idx = tid; idx < 65*128; idx += 256) {
    int fb = idx >> 7, k = idx & 127;
    float wk = 0.5f*(1.0f - cosf(2.0f*PI_F*(float)k/128.0f));
    int ph = (fb*k) & 127;
    float ang = 2.0f*PI_F*(float)ph/128.0f;
    float cv = cosf(ang), sv = sinf(ang);
    ws[OFF_CW + idx] = wk*cv;
    ws[OFF_SW + idx] = -wk*sv;
    float cf = (fb == 0 || fb == 64) ? 1.0f : 2.0f;
    float sc = (1.0f/128.0f)*wk*cf;
    ws[OFF_IC + k*65 + fb] = sc*cv;
    ws[OFF_IS + k*65 + fb] = -sc*sv;
  }
  if (tid < 64) {
    float w0 = 0.5f*(1.0f - cosf(2.0f*PI_F*(float)tid/128.0f));
    float w1 = 0.5f*(1.0f - cosf(2.0f*PI_F*(float)(tid + 64)/128.0f));
    ws[OFF_DEN + tid] = 1.0f/fmaxf(w0*w0 + w1*w1, 1e-11f);
  }
}

// w116[ci][co][k] = fp16(w1[co][ci][k])
__launch_bounds__(256)
__global__ void dfc_prep_w1(const float* __restrict__ w1, u16* __restrict__ w116) {
  int idx = blockIdx.x*256 + threadIdx.x;           // < 524288
  int k8 = idx & 15, rc = idx >> 4;
  int co = rc & 255, ci = rc >> 8;
  const float* src = w1 + ((size_t)(co*128 + ci)*128 + k8*8);
  float4 a = F4(src), b = F4(src + 4);
  half8 hv;
  hv[0]=(h16)a.x; hv[1]=(h16)a.y; hv[2]=(h16)a.z; hv[3]=(h16)a.w;
  hv[4]=(h16)b.x; hv[5]=(h16)b.y; hv[6]=(h16)b.z; hv[7]=(h16)b.w;
  *(half8*)((h16*)w116 + (size_t)idx*8) = hv;
}

// w216[row][c] = fp16(w2[row][c]) with in-row chunk swizzle: chunk c/8 ^ (fb&7)
__launch_bounds__(256)
__global__ void dfc_prep_w2(const float* __restrict__ w2, u16* __restrict__ w216) {
  int idx = blockIdx.x*256 + threadIdx.x;           // < 1064960
  int cc = idx & 31, r = idx >> 5;
  int fb = r % 65;
  const float* src = w2 + (size_t)r*256 + cc*8;
  float4 a = F4(src), b = F4(src + 4);
  half8 hv;
  hv[0]=(h16)a.x; hv[1]=(h16)a.y; hv[2]=(h16)a.z; hv[3]=(h16)a.w;
  hv[4]=(h16)b.x; hv[5]=(h16)b.y; hv[6]=(h16)b.z; hv[7]=(h16)b.w;
  *(half8*)((h16*)w216 + (size_t)r*256 + ((cc ^ (fb & 7)) << 3)) = hv;
}

// conv1 v3: Toeplitz window staging, LDS double-buffer, 1 barrier/ci.
// grid (9,8,8) flat-swizzled: kc = flat&7 (XCD-resident w116 slice)
__launch_bounds__(256, 3)
__global__ void dfc_conv1(const float* __restrict__ cond, const u16* __restrict__ w116,
                          u16* __restrict__ hpart) {
  __shared__ u32 segu[2][2112];
  const int flat = (blockIdx.z*8 + blockIdx.y)*9 + blockIdx.x;
  const int kc = flat & 7;
  const int r9 = flat >> 3;
  const int b  = r9 / 9;
  const int t0 = (r9 - b*9) * 64;
  const int tid = threadIdx.x;
  const int wave = tid >> 6, lane = tid & 63;
  const int l15 = lane & 15, g16 = lane >> 4;
  const int gbase = t0*64 - 64;
  const bool interior = (t0 > 0) && (gbase + 4160 <= TLEN);
  f32x4 acc[4][4] = {};
  const h16* w116h = (const h16*)w116;
  float4 rv[5];

  auto loadci = [&](int ci) {
    const float* cb = cond + (size_t)(b*128 + ci)*TLEN;
    if (interior) {
      #pragma unroll
      for (int kq = 0; kq < 4; ++kq)
        rv[kq] = F4(cb + gbase + 4*(tid + 256*kq));
      if (tid < 16) rv[4] = F4(cb + gbase + 4*(tid + 1024));
    } else {
      #pragma unroll
      for (int kq = 0; kq < 5; ++kq) {
        int q = tid + 256*kq;
        if (q < 1040) {
          int g0 = gbase + 4*q;
          float4 v;
          v.x = (g0   >= 0 && g0   < TLEN) ? cb[g0]   : 0.f;
          v.y = (g0+1 >= 0 && g0+1 < TLEN) ? cb[g0+1] : 0.f;
          v.z = (g0+2 >= 0 && g0+2 < TLEN) ? cb[g0+2] : 0.f;
          v.w = (g0+3 >= 0 && g0+3 < TLEN) ? cb[g0+3] : 0.f;
          rv[kq] = v;
        }
      }
    }
  };
  auto writeci = [&](int buf) {
    #pragma unroll
    for (int kq = 0; kq < 5; ++kq) {
      int q = tid + 256*kq;
      if (kq < 4 || tid < 16) {
        int s2 = 2*q;
        int idx = s2 ^ (((s2 >> 5) & 7) << 2);
        segu[buf][idx]     = (u32)pkh(rv[kq].x) | ((u32)pkh(rv[kq].y) << 16);
        segu[buf][idx + 1] = (u32)pkh(rv[kq].z) | ((u32)pkh(rv[kq].w) << 16);
      }
    }
  };

  loadci(kc*16);
  writeci(0);
  __syncthreads();
  int cur = 0;
  for (int cl = 0; cl < 16; ++cl) {
    const int ci = kc*16 + cl;
    if (cl < 15) loadci(ci + 1);         // issue next-tile loads early (T14)
    const char* sb = (const char*)segu[cur];
    const h16* wb = w116h + (size_t)ci*32768;
    #pragma unroll
    for (int ks = 0; ks < 4; ++ks) {
      half8 Bf[4];
      #pragma unroll
      for (int nt = 0; nt < 4; ++nt) {
        int byte = 128*(nt*16 + l15) + 64*ks + 16*g16;
        byte ^= ((byte >> 7) & 7) << 4;
        Bf[nt] = *(const half8*)(sb + byte);
      }
      #pragma unroll
      for (int mi = 0; mi < 4; ++mi) {
        const int co = (wave*4 + mi)*16 + l15;
        half8 Af = *(const half8*)(wb + co*128 + ks*32 + g16*8);
        #pragma unroll
        for (int nt = 0; nt < 4; ++nt)
          acc[mi][nt] = __builtin_amdgcn_mfma_f32_16x16x32_f16(Af, Bf[nt], acc[mi][nt], 0,0,0);
      }
    }
    if (cl < 15) writeci(cur ^ 1);       // write-late into the other buffer
    __syncthreads();
    cur ^= 1;
  }
  h16* hp = (h16*)hpart;
  #pragma unroll
  for (int mi = 0; mi < 4; ++mi) {
    const int co0 = (wave*4 + mi)*16 + g16*4;
    #pragma unroll
    for (int nt = 0; nt < 4; ++nt) {
      int t = t0 + nt*16 + l15;
      if (t < NFR) {
        half4 v;
        v[0]=(h16)acc[mi][nt][0]; v[1]=(h16)acc[mi][nt][1];
        v[2]=(h16)acc[mi][nt][2]; v[3]=(h16)acc[mi][nt][3];
        *(half4*)(hp + ((size_t)(kc*8 + b)*NFR + t)*256 + co0) = v;
      }
    }
  }
}

// reduce 8 partials + b1 -> hT16[b][t][c] fp16, chunk-swizzled (c/8 ^ (t&7))
__launch_bounds__(256)
__global__ void dfc_hred(const u16* __restrict__ hpart, const float* __restrict__ b1,
                         u16* __restrict__ hT16) {
  int idx = blockIdx.x*256 + threadIdx.x;            // < 131328
  int b = idx / 16416, r = idx % 16416;
  int t = r >> 5, cc = r & 31;
  float s[8];
  float4 ba = F4(&b1[cc*8]), bb = F4(&b1[cc*8 + 4]);
  s[0]=ba.x; s[1]=ba.y; s[2]=ba.z; s[3]=ba.w; s[4]=bb.x; s[5]=bb.y; s[6]=bb.z; s[7]=bb.w;
  const h16* hp = (const h16*)hpart;
  #pragma unroll
  for (int kc = 0; kc < 8; ++kc) {
    half8 hv = *(const half8*)(hp + ((size_t)(kc*8 + b)*NFR + t)*256 + cc*8);
    #pragma unroll
    for (int j = 0; j < 8; ++j) s[j] += (float)hv[j];
  }
  half8 o;
  #pragma unroll
  for (int j = 0; j < 8; ++j) o[j] = (h16)s[j];
  *(half8*)((h16*)hT16 + ((size_t)b*TP + t)*256 + ((cc ^ (t & 7)) << 3)) = o;
}

// STFT -> X16 fp16 [row][p][t(TP)][fb(FP)]
__launch_bounds__(256)
__global__ void dfc_stft(const float* __restrict__ x, const float* __restrict__ wsp,
                         u16* __restrict__ X16) {
  __shared__ __align__(16) float sfr[32*132];
  __shared__ __align__(16) float CWl[32*132];
  __shared__ __align__(16) float SWl[32*132];
  __shared__ __align__(16) u16 Xt[32*136];
  const int row = blockIdx.y, t0 = blockIdx.x*32, tid = threadIdx.x;
  for (int idx = tid; idx < 32*128; idx += 256) {
    int t = idx >> 7, k = idx & 127;
    int g = (t0 + t)*64 + k - 64;
    int s = (g < 0) ? -g : ((g >= TLEN) ? (2*TLEN - 2 - g) : g);
    sfr[t*132 + k] = x[(size_t)row*TLEN + s];
  }
  const int fbl = tid >> 3, tg = tid & 7;
  float aR[3][4], aI[3][4];
  for (int ps = 0; ps < 3; ++ps) {
    const int fbBase = ps*32;
    const int nrows = (fbBase + 32 <= 65) ? 32 : (65 - fbBase);
    __syncthreads();
    for (int idx = tid; idx < nrows*128; idx += 256) {
      int r = idx >> 7, k = idx & 127;
      CWl[r*132 + k] = wsp[OFF_CW + (fbBase + r)*128 + k];
      SWl[r*132 + k] = wsp[OFF_SW + (fbBase + r)*128 + k];
    }
    __syncthreads();
    #pragma unroll
    for (int u = 0; u < 4; ++u) { aR[ps][u] = 0.f; aI[ps][u] = 0.f; }
    if (fbl < nrows) {
      #pragma unroll 4
      for (int k = 0; k < 128; ++k) {
        float cw = CWl[fbl*132 + k], sw = SWl[fbl*132 + k];
        #pragma unroll
        for (int u = 0; u < 4; ++u) {
          float sv = sfr[(tg + 8*u)*132 + k];
          aR[ps][u] += sv*cw;
          aI[ps][u] += sv*sw;
        }
      }
    }
  }
  __syncthreads();
  #pragma unroll
  for (int ps = 0; ps < 3; ++ps) {
    const int fb = ps*32 + fbl;
    if (fb <= 64) {
      #pragma unroll
      for (int u = 0; u < 4; ++u) {
        int tl = tg + 8*u;
        Xt[tl*136 + fb]      = pkh(aR[ps][u]);
        Xt[tl*136 + 68 + fb] = pkh(aI[ps][u]);
      }
    }
  }
  __syncthreads();
  const u32* Xtw = (const u32*)Xt;
  for (int idx = tid; idx < 2176; idx += 256) {
    int tp = idx / 34, dw = idx - tp*34;
    int tl = tp >> 1, p = tp & 1;
    int t = t0 + tl;
    if (t < NFR) {
      u32* dst = (u32*)((h16*)X16 + ((size_t)(row*2 + p)*TP + t)*FP);
      dst[dw] = Xtw[tl*68 + p*34 + dw];
    }
  }
}

// conv2y v2: 64 linearized (i,kk) steps, LDS double-buffer, stage-before-compute,
// single barrier/step. XCD swizzle: b = flat&7 -> X[b]+hT[b] L2-resident per XCD.
__launch_bounds__(256, 2)
__global__ void dfc_conv2y(const u16* __restrict__ w216, const u16* __restrict__ hT16,
                           const float* __restrict__ b2, const u16* __restrict__ X16,
                           u16* __restrict__ Y16) {
  __shared__ __align__(16) char Al[2][16384];
  __shared__ __align__(16) char Bl[2][12288];
  __shared__ h16 b2h[2048];
  const int flat = (blockIdx.z*16 + blockIdx.y)*6 + blockIdx.x;
  const int b  = flat & 7;
  const int r2 = flat >> 3;                          // 0..95
  const int o  = r2 / 6;
  const int t0 = (r2 - o*6) * 96;
  const int tid = threadIdx.x;
  const int wave = tid >> 6, lane = tid & 63;
  const int wp = wave >> 1, wn = wave & 1;
  const int l15 = lane & 15, g16 = lane >> 4;
  const int lrow8 = lane >> 3, lcol = (lane & 7)*16;
  const char* wb = (const char*)w216;
  const char* hb = (const char*)hT16;

  for (int idx = tid; idx < 2048; idx += 256) {
    int p = idx >> 10, rr = idx & 1023, i = rr >> 6, fb = rr & 63;
    b2h[idx] = (h16)b2[(size_t)((p*16 + o)*16 + i)*65 + fb];
  }

  auto stage = [&](int s) {
    const int i = s >> 2, kk = s & 3, buf = s & 1;
    const int rb0 = (o*16 + i)*65, rb1 = (256 + o*16 + i)*65;
    #pragma unroll
    for (int j = 0; j < 4; ++j) {
      int rr = wave*32 + j*8 + lrow8;
      int wrow = (rr < 64) ? (rb0 + rr) : (rb1 + (rr - 64));
      GLDS(wb + (((size_t)wrow*256 + kk*64) << 1) + lcol, &Al[buf][(wave*32 + j*8)*128]);
    }
    #pragma unroll
    for (int j = 0; j < 3; ++j) {
      int tr = wave*24 + j*8 + lrow8;
      GLDS(hb + ((((size_t)b*TP + t0 + tr)*256 + kk*64) << 1) + lcol, &Bl[buf][(wave*24 + j*8)*128]);
    }
  };

  stage(0);
  __syncthreads();
  f32x4 yac[4][3] = {};
  f32x4 fac[4][3];
  for (int s = 0; s < 64; ++s) {
    const int i = s >> 2, kk = s & 3, buf = s & 1;
    if (s < 63) stage(s + 1);                        // prefetch next step
    if (kk == 0) {
      #pragma unroll
      for (int mi = 0; mi < 4; ++mi) {
        half4 bh = *(const half4*)&b2h[(wp*16 + i)*64 + mi*16 + g16*4];
        #pragma unroll
        for (int nt = 0; nt < 3; ++nt) {
          fac[mi][nt][0] = (float)bh[0]; fac[mi][nt][1] = (float)bh[1];
          fac[mi][nt][2] = (float)bh[2]; fac[mi][nt][3] = (float)bh[3];
        }
      }
    }
    #pragma unroll
    for (int ks = 0; ks < 2; ++ks) {
      half8 Af[4], Bf[3];
      #pragma unroll
      for (int mi = 0; mi < 4; ++mi) {
        int rr = wp*64 + mi*16 + l15;
        int byte = rr*128 + ks*64 + g16*16;
        byte ^= (rr & 7) << 4;
        Af[mi] = *(const half8*)(&Al[buf][byte]);
      }
      #pragma unroll
      for (int nt = 0; nt < 3; ++nt) {
        int tr = wn*48 + nt*16 + l15;
        int byte = tr*128 + ks*64 + g16*16;
        byte ^= (tr & 7) << 4;
        Bf[nt] = *(const half8*)(&Bl[buf][byte]);
      }
      #pragma unroll
      for (int mi = 0; mi < 4; ++mi)
        #pragma unroll
        for (int nt = 0; nt < 3; ++nt)
          fac[mi][nt] = __builtin_amdgcn_mfma_f32_16x16x32_f16(Af[mi], Bf[nt], fac[mi][nt], 0,0,0);
    }
    if (kk == 3) {
      const h16* Xrow = (const h16*)X16 + (size_t)((b*16 + i)*2 + wp)*TP*FP;
      #pragma unroll
      for (int mi = 0; mi < 4; ++mi) {
        int fb0 = mi*16 + g16*4;
        #pragma unroll
        for (int nt = 0; nt < 3; ++nt) {
          int t = t0 + wn*48 + nt*16 + l15;
          half4 xv = *(const half4*)(Xrow + (size_t)t*FP + fb0);
          yac[mi][nt][0] += fac[mi][nt][0]*(float)xv[0];
          yac[mi][nt][1] += fac[mi][nt][1]*(float)xv[1];
          yac[mi][nt][2] += fac[mi][nt][2]*(float)xv[2];
          yac[mi][nt][3] += fac[mi][nt][3]*(float)xv[3];
        }
      }
    }
    __syncthreads();
  }
  h16* Yh = (h16*)Y16;
  const int orow = (b*16 + o)*2 + wp;
  #pragma unroll
  for (int mi = 0; mi < 4; ++mi) {
    int fb0 = mi*16 + g16*4;
    #pragma unroll
    for (int nt = 0; nt < 3; ++nt) {
      int t = t0 + wn*48 + nt*16 + l15;
      if (t < NFR) {
        half4 v;
        v[0]=(h16)yac[mi][nt][0]; v[1]=(h16)yac[mi][nt][1];
        v[2]=(h16)yac[mi][nt][2]; v[3]=(h16)yac[mi][nt][3];
        *(half4*)(Yh + ((size_t)orow*NFR + t)*FP + fb0) = v;
      }
    }
  }
}

// fb=64 (Nyquist) slice: f32 dots over contiguous fp16 h rows; t-split grid
__launch_bounds__(256)
__global__ void dfc_edge(const float* __restrict__ w2, const float* __restrict__ b2,
                         const u16* __restrict__ hT16, const u16* __restrict__ X16,
                         u16* __restrict__ Y16) {
  __shared__ float Wl[8192];
  __shared__ float b2l[32];
  const int o = blockIdx.x, b = blockIdx.y, tc = blockIdx.z, tid = threadIdx.x;
  for (int idx = tid; idx < 8192; idx += 256) {
    int pi = idx >> 8, c = idx & 255;
    int p = pi >> 4, i = pi & 15;
    Wl[idx] = w2[(size_t)(((p*16 + o)*16 + i)*65 + 64)*256 + c];
  }
  if (tid < 32) {
    int p = tid >> 4, i = tid & 15;
    b2l[tid] = b2[(size_t)((p*16 + o)*16 + i)*65 + 64];
  }
  __syncthreads();
  const h16* hh = (const h16*)hT16;
  const h16* Xh = (const h16*)X16;
  h16* Yh = (h16*)Y16;
  for (int t = tc*256 + tid; t < NFR; t += 512) {
    int key = t & 7;
    float facc[32];
    #pragma unroll
    for (int pi = 0; pi < 32; ++pi) facc[pi] = b2l[pi];
    const h16* hrow = hh + ((size_t)b*TP + t)*256;
    for (int cc = 0; cc < 32; ++cc) {
      half8 hv = *(const half8*)(hrow + ((cc ^ key) << 3));
      float h0=(float)hv[0], h1=(float)hv[1], h2=(float)hv[2], h3=(float)hv[3];
      float h4=(float)hv[4], h5=(float)hv[5], h6=(float)hv[6], h7=(float)hv[7];
      #pragma unroll
      for (int pi = 0; pi < 32; ++pi) {
        const float* wr = &Wl[pi*256 + cc*8];
        facc[pi] += wr[0]*h0 + wr[1]*h1 + wr[2]*h2 + wr[3]*h3
                  + wr[4]*h4 + wr[5]*h5 + wr[6]*h6 + wr[7]*h7;
      }
    }
    float y0 = 0.f, y1 = 0.f;
    #pragma unroll
    for (int pi = 0; pi < 32; ++pi) {
      int p = pi >> 4, i = pi & 15;
      float xv = (float)Xh[((size_t)((b*16 + i)*2 + p)*TP + t)*FP + 64];
      if (p == 0) y0 += facc[pi]*xv; else y1 += facc[pi]*xv;
    }
    Yh[((size_t)((b*16 + o)*2 + 0)*NFR + t)*FP + 64] = (h16)y0;
    Yh[((size_t)((b*16 + o)*2 + 1)*NFR + t)*FP + 64] = (h16)y1;
  }
}

// iSTFT from Y16 fp16
__launch_bounds__(256)
__global__ void dfc_istft(const u16* __restrict__ Y16, const float* __restrict__ wsp,
                          const float* __restrict__ bias, float* __restrict__ out) {
  __shared__ __align__(16) float Tc[128*36];
  __shared__ __align__(16) float Ts[128*36];
  __shared__ __align__(16) float Yl[2*17*68];
  __shared__ float invden[64];
  const int row = blockIdx.y, u0 = blockIdx.x*16, tid = threadIdx.x;
  const h16* Yh = (const h16*)Y16;
  for (int q = tid; q < 1156; q += 256) {
    int p = q / 578, r = q - p*578, tl = r / 34, fbp = r - tl*34;
    half2v v = *(const half2v*)(Yh + ((size_t)(row*2 + p)*NFR + u0 + tl)*FP + fbp*2);
    Yl[(p*17 + tl)*68 + fbp*2]     = (float)v[0];
    Yl[(p*17 + tl)*68 + fbp*2 + 1] = (float)v[1];
  }
  if (tid < 64) invden[tid] = wsp[OFF_DEN + tid];
  const int k1 = tid & 63, uu = tid >> 6;
  const int kA = k1 + 64, kB = k1;
  float acc[4] = {0,0,0,0};
  for (int half = 0; half < 2; ++half) {
    const int fb0 = half*32, ncol = half ? 33 : 32;
    __syncthreads();
    for (int idx = tid; idx < 128*ncol; idx += 256) {
      int k = idx/ncol, fb = idx - k*ncol;
      Tc[k*36 + fb] = wsp[OFF_IC + k*65 + fb0 + fb];
      Ts[k*36 + fb] = wsp[OFF_IS + k*65 + fb0 + fb];
    }
    __syncthreads();
    #pragma unroll
    for (int it = 0; it < 4; ++it) {
      const int u = it*4 + uu;
      const int tA = u, tB = u + 1;
      float a = 0.f;
      #pragma unroll 2
      for (int f4 = 0; f4 < 8; ++f4) {
        float4 icA = F4(&Tc[kA*36 + f4*4]);
        float4 isA = F4(&Ts[kA*36 + f4*4]);
        float4 icB = F4(&Tc[kB*36 + f4*4]);
        float4 isB = F4(&Ts[kB*36 + f4*4]);
        float4 yrA = F4(&Yl[(0*17 + tA)*68 + fb0 + f4*4]);
        float4 yiA = F4(&Yl[(1*17 + tA)*68 + fb0 + f4*4]);
        float4 yrB = F4(&Yl[(0*17 + tB)*68 + fb0 + f4*4]);
        float4 yiB = F4(&Yl[(1*17 + tB)*68 + fb0 + f4*4]);
        a += icA.x*yrA.x + icA.y*yrA.y + icA.z*yrA.z + icA.w*yrA.w;
        a += isA.x*yiA.x + isA.y*yiA.y + isA.z*yiA.z + isA.w*yiA.w;
        a += icB.x*yrB.x + icB.y*yrB.y + icB.z*yrB.z + icB.w*yrB.w;
        a += isB.x*yiB.x + isB.y*yiB.y + isB.z*yiB.z + isB.w*yiB.w;
      }
      if (half == 1) {
        a += Tc[kA*36 + 32]*Yl[(0*17 + tA)*68 + 64] + Ts[kA*36 + 32]*Yl[(1*17 + tA)*68 + 64];
        a += Tc[kB*36 + 32]*Yl[(0*17 + tB)*68 + 64] + Ts[kB*36 + 32]*Yl[(1*17 + tB)*68 + 64];
      }
      acc[it] += a;
    }
  }
  const float bv = bias[row & 15];
  #pragma unroll
  for (int it = 0; it < 4; ++it) {
    int s = it*256 + tid;
    out[(size_t)row*TLEN + u0*64 + s] = acc[it]*invden[k1] + bv;
  }
}

extern "C" void kernel_launch(void* const* d_in, const int* in_sizes, int n_in,
                              void* d_out, int out_size, void* d_ws, size_t ws_size,
                              hipStream_t stream) {
  (void)in_sizes; (void)n_in; (void)out_size; (void)ws_size;
  const float* x    = (const float*)d_in[0];
  const float* cond = (const float*)d_in[1];
  const float* w1   = (const float*)d_in[2];
  const float* b1   = (const float*)d_in[3];
  const float* w2   = (const float*)d_in[4];
  const float* b2   = (const float*)d_in[5];
  const float* bias = (const float*)d_in[6];
  float* ws  = (float*)d_ws;
  float* out = (float*)d_out;
  u16* R     = (u16*)(ws + OFF_R);      // hpart then w216
  u16* hT16  = (u16*)(ws + OFF_HT);
  u16* X16   = (u16*)(ws + OFF_X16);
  u16* Y16   = (u16*)(ws + OFF_Y16);
  u16* w116  = (u16*)(ws + OFF_W116);

  hipMemsetAsync(hT16, 0, (size_t)8*TP*256*2, stream);
  hipMemsetAsync(X16, 0, (size_t)256*TP*FP*2, stream);
  dfc_tables<<<dim3(1), dim3(256), 0, stream>>>(ws);
  dfc_prep_w1<<<dim3(2048), dim3(256), 0, stream>>>(w1, w116);
  dfc_conv1<<<dim3(9, 8, 8), dim3(256), 0, stream>>>(cond, w116, R);
  dfc_hred<<<dim3(513), dim3(256), 0, stream>>>(R, b1, hT16);
  dfc_prep_w2<<<dim3(4160), dim3(256), 0, stream>>>(w2, R);
  dfc_stft<<<dim3(17, 128), dim3(256), 0, stream>>>(x, ws, X16);
  dfc_conv2y<<<dim3(6, 16, 8), dim3(256), 0, stream>>>(R, hT16, b2, X16, Y16);
  dfc_edge<<<dim3(16, 8, 2), dim3(256), 0, stream>>>(w2, b2, hT16, X16, Y16);
  dfc_istft<<<dim3(32, 128), dim3(256), 0, stream>>>(Y16, ws, bias, out);
}

// Round 5
// 615.870 us; speedup vs baseline: 6.6576x; 1.0169x over previous
//
#include <hip/hip_runtime.h>
#include <math.h>

#define TLEN 32768
#define NFR  513
#define TP   576          // padded frame count
#define PI_F 3.14159265358979323846f

typedef unsigned short u16;
typedef unsigned int   u32;
typedef _Float16 h16;
typedef h16  half8  __attribute__((ext_vector_type(8)));
typedef h16  half4  __attribute__((ext_vector_type(4)));
typedef float f32x4 __attribute__((ext_vector_type(4)));

// float-unit offsets in workspace
#define OFF_CW   0        // [65][128] window*cos
#define OFF_SW   8320     // [65][128] -window*sin
#define OFF_TI   16640    // Tist fp16 [128][160]: istft table, invden folded
#define OFF_R    26880    // region: hpart fp16 [64][513][256] THEN w216 fp16 [33280][256]
#define OFF_HT   4286720  // hT16 fp16 [8][576][256], chunk-swizzled
#define OFF_X16  4876544  // X16 fp16 [128][576][136]
#define OFF_Y16  9890048  // Y16 fp16 [128][513][136]
#define OFF_W116 14355200 // w116 fp16 [128ci][256co][128k]
// end: 16,452,352 floats = 65.8 MB

#define F4(p) (*reinterpret_cast<const float4*>(p))
#define GLDS(gsrc, ldst) __builtin_amdgcn_global_load_lds( \
    (const __attribute__((address_space(1))) void*)(gsrc),  \
    (__attribute__((address_space(3))) void*)(ldst), 16, 0, 0)

__device__ __forceinline__ u16 pkh(float v) { return __builtin_bit_cast(u16, (h16)v); }

__global__ void dfc_tables(float* __restrict__ ws) {
  int tid = threadIdx.x;
  for (int idx = tid; idx < 65*128; idx += 256) {
    int fb = idx >> 7, k = idx & 127;
    float wk = 0.5f*(1.0f - cosf(2.0f*PI_F*(float)k/128.0f));
    int ph = (fb*k) & 127;
    float ang = 2.0f*PI_F*(float)ph/128.0f;
    ws[OFF_CW + idx] = wk*cosf(ang);
    ws[OFF_SW + idx] = -wk*sinf(ang);
  }
  // Tist[k][c]: c = p*68+fb; IC/IS * invden(k&63); rows padded to 160, pads zero
  u16* Ti = (u16*)(ws + OFF_TI);
  for (int idx = tid; idx < 128*160; idx += 256) {
    int k = idx / 160, c = idx - k*160;
    float v = 0.0f;
    if (c < 136) {
      int p = c / 68, fb = c - p*68;
      if (fb <= 64) {
        float wk = 0.5f*(1.0f - cosf(2.0f*PI_F*(float)k/128.0f));
        float cf = (fb == 0 || fb == 64) ? 1.0f : 2.0f;
        float sc = (1.0f/128.0f)*wk*cf;
        int ph = (fb*k) & 127;
        float ang = 2.0f*PI_F*(float)ph/128.0f;
        int j = k & 63;
        float w0 = 0.5f*(1.0f - cosf(2.0f*PI_F*(float)j/128.0f));
        float w1 = 0.5f*(1.0f - cosf(2.0f*PI_F*(float)(j+64)/128.0f));
        float inv = 1.0f/fmaxf(w0*w0 + w1*w1, 1e-11f);
        v = ((p == 0) ? sc*cosf(ang) : -sc*sinf(ang)) * inv;
      }
    }
    Ti[idx] = pkh(v);
  }
}

// w116[ci][co][k] = fp16(w1[co][ci][k])
__launch_bounds__(256)
__global__ void dfc_prep_w1(const float* __restrict__ w1, u16* __restrict__ w116) {
  int idx = blockIdx.x*256 + threadIdx.x;           // < 524288
  int k8 = idx & 15, rc = idx >> 4;
  int co = rc & 255, ci = rc >> 8;
  const float* src = w1 + ((size_t)(co*128 + ci)*128 + k8*8);
  float4 a = F4(src), b = F4(src + 4);
  half8 hv;
  hv[0]=(h16)a.x; hv[1]=(h16)a.y; hv[2]=(h16)a.z; hv[3]=(h16)a.w;
  hv[4]=(h16)b.x; hv[5]=(h16)b.y; hv[6]=(h16)b.z; hv[7]=(h16)b.w;
  *(half8*)((h16*)w116 + (size_t)idx*8) = hv;
}

// w216[row][c] = fp16(w2[row][c]) with in-row chunk swizzle: chunk c/8 ^ (fb&7)
__launch_bounds__(256)
__global__ void dfc_prep_w2(const float* __restrict__ w2, u16* __restrict__ w216) {
  int idx = blockIdx.x*256 + threadIdx.x;           // < 1064960
  int cc = idx & 31, r = idx >> 5;
  int fb = r % 65;
  const float* src = w2 + (size_t)r*256 + cc*8;
  float4 a = F4(src), b = F4(src + 4);
  half8 hv;
  hv[0]=(h16)a.x; hv[1]=(h16)a.y; hv[2]=(h16)a.z; hv[3]=(h16)a.w;
  hv[4]=(h16)b.x; hv[5]=(h16)b.y; hv[6]=(h16)b.z; hv[7]=(h16)b.w;
  *(half8*)((h16*)w216 + (size_t)r*256 + ((cc ^ (fb & 7)) << 3)) = hv;
}

// conv1 v5.1: 32-frame tiles, 4-buffer f32-in-LDS glds pipeline, counted vmcnt,
// raw barriers. grid (17,8,8); kc = linear&7 (XCD-resident w116 slice).
// FIX vs v5: B-fragment float index is 64*f+32*ks+8*g16 (was erroneously 2x).
__launch_bounds__(256, 4)
__global__ void dfc_conv1(const float* __restrict__ cond, const u16* __restrict__ w116,
                          u16* __restrict__ hpart) {
  __shared__ __align__(16) float seg[4][2112];     // 4 x 8448 B
  const int flat = (blockIdx.z*8 + blockIdx.y)*17 + blockIdx.x;
  const int kc = flat & 7;
  const int r9 = flat >> 3;                        // 0..135
  const int b  = r9 / 17;
  const int tile = r9 - b*17;
  const int t0 = tile*32;
  const int tid = threadIdx.x;
  const int wave = tid >> 6, lane = tid & 63;
  const int l15 = lane & 15, g16 = lane >> 4;
  const int gbase4 = (t0*64 - 64)*4;               // byte base (may be -256)
  const bool edgeb = (tile == 0) || (tile == 16);

  // static per-round staging info; source pre-swizzled so LDS stays linear
  int srcL[3]; bool actv[3];
  #pragma unroll
  for (int r = 0; r < 3; ++r) {
    int c = wave*132 + r*64 + lane;                // 16B chunk 0..527
    int L = 16*(c ^ ((c >> 5) & 15));              // logical byte for phys chunk c
    srcL[r] = L;
    bool act = (r < 2) || (lane < 4);
    actv[r] = act && (gbase4 + L >= 0) && (gbase4 + L < TLEN*4);
  }
  if (edgeb) {                                     // pad slots stay zero forever
    float* sf = &seg[0][0];
    for (int i = tid; i < 4*2112; i += 256) sf[i] = 0.0f;
  }
  __syncthreads();

  const h16* w116h = (const h16*)w116;
  f32x4 acc[4][2] = {};

  auto stage = [&](int cl) {
    const char* cbB = (const char*)(cond + (size_t)(b*128 + kc*16 + cl)*TLEN);
    char* dst = (char*)&seg[cl & 3][0];
    #pragma unroll
    for (int r = 0; r < 3; ++r) {
      if (actv[r])
        GLDS(cbB + (gbase4 + srcL[r]), dst + (wave*132 + r*64)*16);
    }
  };

  stage(0); stage(1); stage(2);

  for (int cl = 0; cl < 16; ++cl) {
    if (edgeb) asm volatile("s_waitcnt vmcnt(0)" ::: "memory");
    else       asm volatile("s_waitcnt vmcnt(6)" ::: "memory");
    __builtin_amdgcn_s_barrier();
    __builtin_amdgcn_sched_barrier(0);
    const char* sb = (const char*)&seg[cl & 3][0];
    const h16* wb = w116h + (size_t)(kc*16 + cl)*32768;
    #pragma unroll
    for (int ks = 0; ks < 4; ++ks) {
      half8 Bf[2];
      #pragma unroll
      for (int nt = 0; nt < 2; ++nt) {
        int fi = 64*(nt*16 + l15) + 32*ks + 8*g16;   // float index in window
        int L0 = 4*fi;
        int P0 = L0 ^ (((L0 >> 9) & 15) << 4);
        int L1 = L0 + 16;
        int P1 = L1 ^ (((L1 >> 9) & 15) << 4);
        float4 b0 = F4(sb + P0);
        float4 b1 = F4(sb + P1);
        half8 h;
        h[0]=(h16)b0.x; h[1]=(h16)b0.y; h[2]=(h16)b0.z; h[3]=(h16)b0.w;
        h[4]=(h16)b1.x; h[5]=(h16)b1.y; h[6]=(h16)b1.z; h[7]=(h16)b1.w;
        Bf[nt] = h;
      }
      #pragma unroll
      for (int mi = 0; mi < 4; ++mi) {
        const int co = (wave*4 + mi)*16 + l15;
        half8 Af = *(const half8*)(wb + co*128 + ks*32 + g16*8);
        acc[mi][0] = __builtin_amdgcn_mfma_f32_16x16x32_f16(Af, Bf[0], acc[mi][0], 0,0,0);
        acc[mi][1] = __builtin_amdgcn_mfma_f32_16x16x32_f16(Af, Bf[1], acc[mi][1], 0,0,0);
      }
    }
    if (cl < 13) stage(cl + 3);
  }
  h16* hp = (h16*)hpart;
  #pragma unroll
  for (int mi = 0; mi < 4; ++mi) {
    const int co0 = (wave*4 + mi)*16 + g16*4;
    #pragma unroll
    for (int nt = 0; nt < 2; ++nt) {
      int t = t0 + nt*16 + l15;
      if (t < NFR) {
        half4 v;
        v[0]=(h16)acc[mi][nt][0]; v[1]=(h16)acc[mi][nt][1];
        v[2]=(h16)acc[mi][nt][2]; v[3]=(h16)acc[mi][nt][3];
        *(half4*)(hp + ((size_t)(kc*8 + b)*NFR + t)*256 + co0) = v;
      }
    }
  }
}

// reduce 8 partials + b1 -> hT16[b][t][c] fp16, chunk-swizzled (c/8 ^ (t&7))
__launch_bounds__(256)
__global__ void dfc_hred(const u16* __restrict__ hpart, const float* __restrict__ b1,
                         u16* __restrict__ hT16) {
  int idx = blockIdx.x*256 + threadIdx.x;            // < 131328
  int b = idx / 16416, r = idx % 16416;
  int t = r >> 5, cc = r & 31;
  float s[8];
  float4 ba = F4(&b1[cc*8]), bb = F4(&b1[cc*8 + 4]);
  s[0]=ba.x; s[1]=ba.y; s[2]=ba.z; s[3]=ba.w; s[4]=bb.x; s[5]=bb.y; s[6]=bb.z; s[7]=bb.w;
  const h16* hp = (const h16*)hpart;
  #pragma unroll
  for (int kc = 0; kc < 8; ++kc) {
    half8 hv = *(const half8*)(hp + ((size_t)(kc*8 + b)*NFR + t)*256 + cc*8);
    #pragma unroll
    for (int j = 0; j < 8; ++j) s[j] += (float)hv[j];
  }
  half8 o;
  #pragma unroll
  for (int j = 0; j < 8; ++j) o[j] = (h16)s[j];
  *(half8*)((h16*)hT16 + ((size_t)b*TP + t)*256 + ((cc ^ (t & 7)) << 3)) = o;
}

// STFT -> X16 fp16 [row][t(TP)][136]  (c = p*68+fb)
__launch_bounds__(256)
__global__ void dfc_stft(const float* __restrict__ x, const float* __restrict__ wsp,
                         u16* __restrict__ X16) {
  __shared__ __align__(16) float sfr[32*132];
  __shared__ __align__(16) float CWl[32*132];
  __shared__ __align__(16) float SWl[32*132];
  __shared__ __align__(16) u16 Xt[32*136];
  const int row = blockIdx.y, t0 = blockIdx.x*32, tid = threadIdx.x;
  for (int idx = tid; idx < 32*128; idx += 256) {
    int t = idx >> 7, k = idx & 127;
    int g = (t0 + t)*64 + k - 64;
    int s = (g < 0) ? -g : ((g >= TLEN) ? (2*TLEN - 2 - g) : g);
    sfr[t*132 + k] = x[(size_t)row*TLEN + s];
  }
  const int fbl = tid >> 3, tg = tid & 7;
  float aR[3][4], aI[3][4];
  for (int ps = 0; ps < 3; ++ps) {
    const int fbBase = ps*32;
    const int nrows = (fbBase + 32 <= 65) ? 32 : (65 - fbBase);
    __syncthreads();
    for (int idx = tid; idx < nrows*128; idx += 256) {
      int r = idx >> 7, k = idx & 127;
      CWl[r*132 + k] = wsp[OFF_CW + (fbBase + r)*128 + k];
      SWl[r*132 + k] = wsp[OFF_SW + (fbBase + r)*128 + k];
    }
    __syncthreads();
    #pragma unroll
    for (int u = 0; u < 4; ++u) { aR[ps][u] = 0.f; aI[ps][u] = 0.f; }
    if (fbl < nrows) {
      #pragma unroll 4
      for (int k = 0; k < 128; ++k) {
        float cw = CWl[fbl*132 + k], sw = SWl[fbl*132 + k];
        #pragma unroll
        for (int u = 0; u < 4; ++u) {
          float sv = sfr[(tg + 8*u)*132 + k];
          aR[ps][u] += sv*cw;
          aI[ps][u] += sv*sw;
        }
      }
    }
  }
  __syncthreads();
  #pragma unroll
  for (int ps = 0; ps < 3; ++ps) {
    const int fb = ps*32 + fbl;
    if (fb <= 64) {
      #pragma unroll
      for (int u = 0; u < 4; ++u) {
        int tl = tg + 8*u;
        Xt[tl*136 + fb]      = pkh(aR[ps][u]);
        Xt[tl*136 + 68 + fb] = pkh(aI[ps][u]);
      }
    }
  }
  __syncthreads();
  const u32* Xtw = (const u32*)Xt;
  for (int idx = tid; idx < 32*68; idx += 256) {
    int tl = idx / 68, dw = idx - tl*68;
    int t = t0 + tl;
    if (t < NFR) {
      u32* dst = (u32*)((h16*)X16 + ((size_t)row*TP + t)*136);
      dst[dw] = Xtw[tl*68 + dw];
    }
  }
}

// conv2y: counted-vmcnt pipeline, raw barriers. 64 (i,kk) steps, dbuf LDS.
__launch_bounds__(256, 2)
__global__ void dfc_conv2y(const u16* __restrict__ w216, const u16* __restrict__ hT16,
                           const float* __restrict__ b2, const u16* __restrict__ X16,
                           u16* __restrict__ Y16) {
  __shared__ __align__(16) char Al[2][16384];
  __shared__ __align__(16) char Bl[2][12288];
  __shared__ h16 b2h[2048];
  const int flat = (blockIdx.z*16 + blockIdx.y)*6 + blockIdx.x;
  const int b  = flat & 7;
  const int r2 = flat >> 3;
  const int o  = r2 / 6;
  const int t0 = (r2 - o*6) * 96;
  const int tid = threadIdx.x;
  const int wave = tid >> 6, lane = tid & 63;
  const int wp = wave >> 1, wn = wave & 1;
  const int l15 = lane & 15, g16 = lane >> 4;
  const int lrow8 = lane >> 3, lcol = (lane & 7)*16;
  const char* wb = (const char*)w216;
  const char* hb = (const char*)hT16;

  for (int idx = tid; idx < 2048; idx += 256) {
    int p = idx >> 10, rr = idx & 1023, i = rr >> 6, fb = rr & 63;
    b2h[idx] = (h16)b2[(size_t)((p*16 + o)*16 + i)*65 + fb];
  }

  auto stage = [&](int s) {
    const int i = s >> 2, kk = s & 3, buf = s & 1;
    const int rb0 = (o*16 + i)*65, rb1 = (256 + o*16 + i)*65;
    #pragma unroll
    for (int j = 0; j < 4; ++j) {
      int rr = wave*32 + j*8 + lrow8;
      int wrow = (rr < 64) ? (rb0 + rr) : (rb1 + (rr - 64));
      GLDS(wb + (((size_t)wrow*256 + kk*64) << 1) + lcol, &Al[buf][(wave*32 + j*8)*128]);
    }
    #pragma unroll
    for (int j = 0; j < 3; ++j) {
      int tr = wave*24 + j*8 + lrow8;
      GLDS(hb + ((((size_t)b*TP + t0 + tr)*256 + kk*64) << 1) + lcol, &Bl[buf][(wave*24 + j*8)*128]);
    }
  };

  stage(0);
  __syncthreads();                                  // drains stage(0) + b2h writes (once)
  f32x4 yac[4][3] = {};
  f32x4 fac[4][3];
  for (int s = 0; s < 64; ++s) {
    const int i = s >> 2, kk = s & 3, buf = s & 1;
    if (s < 63) {
      stage(s + 1);
      asm volatile("s_waitcnt vmcnt(7)" ::: "memory");  // stage(s) arrived; s+1 in flight
    } else {
      asm volatile("s_waitcnt vmcnt(0)" ::: "memory");
    }
    __builtin_amdgcn_s_barrier();
    __builtin_amdgcn_sched_barrier(0);
    if (kk == 0) {
      #pragma unroll
      for (int mi = 0; mi < 4; ++mi) {
        half4 bh = *(const half4*)&b2h[(wp*16 + i)*64 + mi*16 + g16*4];
        #pragma unroll
        for (int nt = 0; nt < 3; ++nt) {
          fac[mi][nt][0] = (float)bh[0]; fac[mi][nt][1] = (float)bh[1];
          fac[mi][nt][2] = (float)bh[2]; fac[mi][nt][3] = (float)bh[3];
        }
      }
    }
    #pragma unroll
    for (int ks = 0; ks < 2; ++ks) {
      half8 Af[4], Bf[3];
      #pragma unroll
      for (int mi = 0; mi < 4; ++mi) {
        int rr = wp*64 + mi*16 + l15;
        int byte = rr*128 + ks*64 + g16*16;
        byte ^= (rr & 7) << 4;
        Af[mi] = *(const half8*)(&Al[buf][byte]);
      }
      #pragma unroll
      for (int nt = 0; nt < 3; ++nt) {
        int tr = wn*48 + nt*16 + l15;
        int byte = tr*128 + ks*64 + g16*16;
        byte ^= (tr & 7) << 4;
        Bf[nt] = *(const half8*)(&Bl[buf][byte]);
      }
      #pragma unroll
      for (int mi = 0; mi < 4; ++mi)
        #pragma unroll
        for (int nt = 0; nt < 3; ++nt)
          fac[mi][nt] = __builtin_amdgcn_mfma_f32_16x16x32_f16(Af[mi], Bf[nt], fac[mi][nt], 0,0,0);
    }
    if (kk == 3) {
      const h16* Xrow = (const h16*)X16 + (size_t)(b*16 + i)*TP*136;
      #pragma unroll
      for (int mi = 0; mi < 4; ++mi) {
        int fb0 = mi*16 + g16*4;
        #pragma unroll
        for (int nt = 0; nt < 3; ++nt) {
          int t = t0 + wn*48 + nt*16 + l15;
          half4 xv = *(const half4*)(Xrow + (size_t)t*136 + wp*68 + fb0);
          yac[mi][nt][0] += fac[mi][nt][0]*(float)xv[0];
          yac[mi][nt][1] += fac[mi][nt][1]*(float)xv[1];
          yac[mi][nt][2] += fac[mi][nt][2]*(float)xv[2];
          yac[mi][nt][3] += fac[mi][nt][3]*(float)xv[3];
        }
      }
    }
    __builtin_amdgcn_s_barrier();
  }
  h16* Yh = (h16*)Y16;
  #pragma unroll
  for (int mi = 0; mi < 4; ++mi) {
    int fb0 = mi*16 + g16*4;
    #pragma unroll
    for (int nt = 0; nt < 3; ++nt) {
      int t = t0 + wn*48 + nt*16 + l15;
      if (t < NFR) {
        half4 v;
        v[0]=(h16)yac[mi][nt][0]; v[1]=(h16)yac[mi][nt][1];
        v[2]=(h16)yac[mi][nt][2]; v[3]=(h16)yac[mi][nt][3];
        *(half4*)(Yh + ((size_t)(b*16 + o)*NFR + t)*136 + wp*68 + fb0) = v;
      }
    }
  }
}

// fb=64 (Nyquist) slice
__launch_bounds__(256)
__global__ void dfc_edge(const float* __restrict__ w2, const float* __restrict__ b2,
                         const u16* __restrict__ hT16, const u16* __restrict__ X16,
                         u16* __restrict__ Y16) {
  __shared__ float Wl[8192];
  __shared__ float b2l[32];
  const int o = blockIdx.x, b = blockIdx.y, tc = blockIdx.z, tid = threadIdx.x;
  for (int idx = tid; idx < 8192; idx += 256) {
    int pi = idx >> 8, c = idx & 255;
    int p = pi >> 4, i = pi & 15;
    Wl[idx] = w2[(size_t)(((p*16 + o)*16 + i)*65 + 64)*256 + c];
  }
  if (tid < 32) {
    int p = tid >> 4, i = tid & 15;
    b2l[tid] = b2[(size_t)((p*16 + o)*16 + i)*65 + 64];
  }
  __syncthreads();
  const h16* hh = (const h16*)hT16;
  const h16* Xh = (const h16*)X16;
  h16* Yh = (h16*)Y16;
  for (int t = tc*256 + tid; t < NFR; t += 512) {
    int key = t & 7;
    float facc[32];
    #pragma unroll
    for (int pi = 0; pi < 32; ++pi) facc[pi] = b2l[pi];
    const h16* hrow = hh + ((size_t)b*TP + t)*256;
    for (int cc = 0; cc < 32; ++cc) {
      half8 hv = *(const half8*)(hrow + ((cc ^ key) << 3));
      float h0=(float)hv[0], h1=(float)hv[1], h2=(float)hv[2], h3=(float)hv[3];
      float h4=(float)hv[4], h5=(float)hv[5], h6=(float)hv[6], h7=(float)hv[7];
      #pragma unroll
      for (int pi = 0; pi < 32; ++pi) {
        const float* wr = &Wl[pi*256 + cc*8];
        facc[pi] += wr[0]*h0 + wr[1]*h1 + wr[2]*h2 + wr[3]*h3
                  + wr[4]*h4 + wr[5]*h5 + wr[6]*h6 + wr[7]*h7;
      }
    }
    float y0 = 0.f, y1 = 0.f;
    #pragma unroll
    for (int pi = 0; pi < 32; ++pi) {
      int p = pi >> 4, i = pi & 15;
      float xv = (float)Xh[((size_t)(b*16 + i)*TP + t)*136 + p*68 + 64];
      if (p == 0) y0 += facc[pi]*xv; else y1 += facc[pi]*xv;
    }
    Yh[((size_t)(b*16 + o)*NFR + t)*136 + 0*68 + 64] = (h16)y0;
    Yh[((size_t)(b*16 + o)*NFR + t)*136 + 1*68 + 64] = (h16)y1;
  }
}

// iSTFT v2: MFMA fr = Tist[128k x 136c] * Yl[136c x t], OLA in LDS, invden in table
__launch_bounds__(256)
__global__ void dfc_istft(const u16* __restrict__ Y16, const float* __restrict__ wsp,
                          const float* __restrict__ bias, float* __restrict__ out) {
  __shared__ __align__(16) char YL[80*336];        // 26880 B; reused as outT[64][68] f32
  const int u = blockIdx.x, row = blockIdx.y, tid = threadIdx.x;
  const int wave = tid >> 6, lane = tid & 63;
  const int l15 = lane & 15, g16 = lane >> 4;
  for (int i = tid; i < 1680; i += 256) ((float4*)YL)[i] = float4{0.f,0.f,0.f,0.f};
  __syncthreads();
  const char* Yb = (const char*)Y16 + ((size_t)row*NFR + u*64)*272;
  for (int ch = tid; ch < 1105; ch += 256) {       // 65 rows x 17 chunks
    int tl = ch / 17, cc = ch - tl*17;
    float4 v = F4(Yb + (size_t)tl*272 + cc*16);
    *(float4*)(YL + tl*336 + cc*16) = v;
  }
  __syncthreads();
  const h16* Ti = (const h16*)(wsp + OFF_TI);
  f32x4 acc[2][5] = {};
  #pragma unroll
  for (int ks = 0; ks < 5; ++ks) {
    half8 Af[2];
    #pragma unroll
    for (int m = 0; m < 2; ++m)
      Af[m] = *(const half8*)(Ti + (size_t)((wave*2 + m)*16 + l15)*160 + ks*32 + g16*8);
    #pragma unroll
    for (int nt = 0; nt < 5; ++nt) {
      half8 Bf = *(const half8*)(YL + (nt*16 + l15)*336 + ks*64 + g16*16);
      acc[0][nt] = __builtin_amdgcn_mfma_f32_16x16x32_f16(Af[0], Bf, acc[0][nt], 0,0,0);
      acc[1][nt] = __builtin_amdgcn_mfma_f32_16x16x32_f16(Af[1], Bf, acc[1][nt], 0,0,0);
    }
  }
  __syncthreads();
  float* outT = (float*)YL;                        // [64][68]
  if (wave >= 2) {                                 // k>=64: out[t][k-64] = val
    #pragma unroll
    for (int m = 0; m < 2; ++m) {
      int j0 = (wave*2 + m - 4)*16 + g16*4;
      #pragma unroll
      for (int nt = 0; nt < 4; ++nt) {
        int t = nt*16 + l15;
        *(f32x4*)&outT[t*68 + j0] = acc[m][nt];
      }
    }
  }
  __syncthreads();
  if (wave < 2) {                                  // k<64: out[t-1][k] += val
    #pragma unroll
    for (int m = 0; m < 2; ++m) {
      int j0 = (wave*2 + m)*16 + g16*4;
      #pragma unroll
      for (int nt = 0; nt < 5; ++nt) {
        int t = nt*16 + l15;
        if (t >= 1 && t <= 64) {
          f32x4 v = *(f32x4*)&outT[(t-1)*68 + j0];
          v[0] += acc[m][nt][0]; v[1] += acc[m][nt][1];
          v[2] += acc[m][nt][2]; v[3] += acc[m][nt][3];
          *(f32x4*)&outT[(t-1)*68 + j0] = v;
        }
      }
    }
  }
  __syncthreads();
  const float bv = bias[row & 15];
  float* og = out + (size_t)row*TLEN + (size_t)u*4096;
  #pragma unroll
  for (int r = 0; r < 4; ++r) {
    int fi = tid + 256*r;
    int sg = fi >> 4, jj = (fi & 15)*4;
    float4 v = *(float4*)&outT[sg*68 + jj];
    float4 w{v.x + bv, v.y + bv, v.z + bv, v.w + bv};
    *(float4*)(og + sg*64 + jj) = w;
  }
}

extern "C" void kernel_launch(void* const* d_in, const int* in_sizes, int n_in,
                              void* d_out, int out_size, void* d_ws, size_t ws_size,
                              hipStream_t stream) {
  (void)in_sizes; (void)n_in; (void)out_size; (void)ws_size;
  const float* x    = (const float*)d_in[0];
  const float* cond = (const float*)d_in[1];
  const float* w1   = (const float*)d_in[2];
  const float* b1   = (const float*)d_in[3];
  const float* w2   = (const float*)d_in[4];
  const float* b2   = (const float*)d_in[5];
  const float* bias = (const float*)d_in[6];
  float* ws  = (float*)d_ws;
  float* out = (float*)d_out;
  u16* R     = (u16*)(ws + OFF_R);      // hpart then w216
  u16* hT16  = (u16*)(ws + OFF_HT);
  u16* X16   = (u16*)(ws + OFF_X16);
  u16* Y16   = (u16*)(ws + OFF_Y16);
  u16* w116  = (u16*)(ws + OFF_W116);

  hipMemsetAsync(hT16, 0, (size_t)8*TP*256*2, stream);
  hipMemsetAsync(X16, 0, (size_t)128*TP*136*2, stream);
  dfc_tables<<<dim3(1), dim3(256), 0, stream>>>(ws);
  dfc_prep_w1<<<dim3(2048), dim3(256), 0, stream>>>(w1, w116);
  dfc_conv1<<<dim3(17, 8, 8), dim3(256), 0, stream>>>(cond, w116, R);
  dfc_hred<<<dim3(513), dim3(256), 0, stream>>>(R, b1, hT16);
  dfc_prep_w2<<<dim3(4160), dim3(256), 0, stream>>>(w2, R);
  dfc_stft<<<dim3(17, 128), dim3(256), 0, stream>>>(x, ws, X16);
  dfc_conv2y<<<dim3(6, 16, 8), dim3(256), 0, stream>>>(R, hT16, b2, X16, Y16);
  dfc_edge<<<dim3(16, 8, 2), dim3(256), 0, stream>>>(w2, b2, hT16, X16, Y16);
  dfc_istft<<<dim3(8, 128), dim3(256), 0, stream>>>(Y16, ws, bias, out);
}

// Round 6
// 514.644 us; speedup vs baseline: 7.9672x; 1.1967x over previous
//
#include <hip/hip_runtime.h>
#include <math.h>

#define TLEN 32768
#define NFR  513
#define TP   576          // padded frame count
#define PI_F 3.14159265358979323846f

typedef unsigned short u16;
typedef unsigned int   u32;
typedef _Float16 h16;
typedef h16  half8  __attribute__((ext_vector_type(8)));
typedef h16  half4  __attribute__((ext_vector_type(4)));
typedef float f32x4 __attribute__((ext_vector_type(4)));

// float-unit offsets in workspace
#define OFF_TST  0         // Tst h16 [144][128]: stft DFT table (window folded)
#define OFF_TI   9216      // Tist h16 [128][160]: istft table, invden folded
#define OFF_B2P  19456     // b2p h16 [512][64]: b2 repack [(o,i,p)][fb]
#define OFF_R    35840     // hpart h16 [64][513][256] THEN w216 h16 [33280][256]
#define OFF_HT   4295680   // hT16 h16 [8][576][256], chunk-swizzled
#define OFF_X16  4885504   // X16 h16 [128][576][136]
#define OFF_Y16  9899008   // Y16 h16 [128][513][136]
#define OFF_W116 14364160  // w116 h16 [128ci][256co][128k]
// end: 16,461,312 floats = 65.8 MB

#define F4(p) (*reinterpret_cast<const float4*>(p))
#define GLDS(gsrc, ldst) __builtin_amdgcn_global_load_lds( \
    (const __attribute__((address_space(1))) void*)(gsrc),  \
    (__attribute__((address_space(3))) void*)(ldst), 16, 0, 0)

__device__ __forceinline__ u16 pkh(float v) { return __builtin_bit_cast(u16, (h16)v); }

__global__ void dfc_tables(float* __restrict__ ws) {
  int tid = threadIdx.x;
  // Tst[c][k], c = p*68+fb: stft DFT rows (pads zero)
  u16* Ts = (u16*)(ws + OFF_TST);
  for (int idx = tid; idx < 144*128; idx += 256) {
    int c = idx >> 7, k = idx & 127;
    float v = 0.0f;
    if (c < 136) {
      int p = c / 68, fb = c - p*68;
      if (fb <= 64) {
        float wk = 0.5f*(1.0f - cosf(2.0f*PI_F*(float)k/128.0f));
        float ang = 2.0f*PI_F*(float)((fb*k) & 127)/128.0f;
        v = (p == 0) ? wk*cosf(ang) : -wk*sinf(ang);
      }
    }
    Ts[idx] = pkh(v);
  }
  // Tist[k][c]: istft table, invden folded; rows padded to 160
  u16* Ti = (u16*)(ws + OFF_TI);
  for (int idx = tid; idx < 128*160; idx += 256) {
    int k = idx / 160, c = idx - k*160;
    float v = 0.0f;
    if (c < 136) {
      int p = c / 68, fb = c - p*68;
      if (fb <= 64) {
        float wk = 0.5f*(1.0f - cosf(2.0f*PI_F*(float)k/128.0f));
        float cf = (fb == 0 || fb == 64) ? 1.0f : 2.0f;
        float sc = (1.0f/128.0f)*wk*cf;
        float ang = 2.0f*PI_F*(float)((fb*k) & 127)/128.0f;
        int j = k & 63;
        float w0 = 0.5f*(1.0f - cosf(2.0f*PI_F*(float)j/128.0f));
        float w1 = 0.5f*(1.0f - cosf(2.0f*PI_F*(float)(j+64)/128.0f));
        float inv = 1.0f/fmaxf(w0*w0 + w1*w1, 1e-11f);
        v = ((p == 0) ? sc*cosf(ang) : -sc*sinf(ang)) * inv;
      }
    }
    Ti[idx] = pkh(v);
  }
}

// w116[ci][co][k] = fp16(w1[co][ci][k])
__launch_bounds__(256)
__global__ void dfc_prep_w1(const float* __restrict__ w1, u16* __restrict__ w116) {
  int idx = blockIdx.x*256 + threadIdx.x;           // < 524288
  int k8 = idx & 15, rc = idx >> 4;
  int co = rc & 255, ci = rc >> 8;
  const float* src = w1 + ((size_t)(co*128 + ci)*128 + k8*8);
  float4 a = F4(src), b = F4(src + 4);
  half8 hv;
  hv[0]=(h16)a.x; hv[1]=(h16)a.y; hv[2]=(h16)a.z; hv[3]=(h16)a.w;
  hv[4]=(h16)b.x; hv[5]=(h16)b.y; hv[6]=(h16)b.z; hv[7]=(h16)b.w;
  *(half8*)((h16*)w116 + (size_t)idx*8) = hv;
}

// w216[row][c] = fp16(w2[row][c]) with in-row chunk swizzle: chunk c/8 ^ (fb&7)
__launch_bounds__(256)
__global__ void dfc_prep_w2(const float* __restrict__ w2, u16* __restrict__ w216) {
  int idx = blockIdx.x*256 + threadIdx.x;           // < 1064960
  int cc = idx & 31, r = idx >> 5;
  int fb = r % 65;
  const float* src = w2 + (size_t)r*256 + cc*8;
  float4 a = F4(src), b = F4(src + 4);
  half8 hv;
  hv[0]=(h16)a.x; hv[1]=(h16)a.y; hv[2]=(h16)a.z; hv[3]=(h16)a.w;
  hv[4]=(h16)b.x; hv[5]=(h16)b.y; hv[6]=(h16)b.z; hv[7]=(h16)b.w;
  *(half8*)((h16*)w216 + (size_t)r*256 + ((cc ^ (fb & 7)) << 3)) = hv;
}

// b2p[((o*16+i)*2+p)*64 + fb] = fp16(b2[((p*16+o)*16+i)*65 + fb]), fb<64
__launch_bounds__(256)
__global__ void dfc_prep_b2(const float* __restrict__ b2, u16* __restrict__ b2p) {
  int idx = blockIdx.x*256 + threadIdx.x;           // < 32768
  int fb = idx & 63, r = idx >> 6;
  int p = r & 1, oi = r >> 1, o = oi >> 4, i = oi & 15;
  ((h16*)b2p)[idx] = (h16)b2[(size_t)((p*16 + o)*16 + i)*65 + fb];
}

// conv1 v6: 96-frame tiles, Toeplitz fp16 window in LDS (round-3 XOR scheme),
// reg-staged T14 pipeline, 96 MFMA per wave per ci step.
// grid (6,8,8); kc = flat&7 (XCD-resident w116 slice).
__launch_bounds__(256)
__global__ void dfc_conv1(const float* __restrict__ cond, const u16* __restrict__ w116,
                          u16* __restrict__ hpart) {
  __shared__ __align__(16) u32 segu[2][3104];       // 2 x 12416 B fp16 window
  const int flat = (blockIdx.z*8 + blockIdx.y)*6 + blockIdx.x;
  const int kc = flat & 7;
  const int rem = flat >> 3;                        // 0..47
  const int b  = rem / 6;
  const int tile = rem - b*6;
  const int t0 = (tile < 5) ? tile*96 : 417;        // tile5 overlaps tile4 (dup writes)
  const int tid = threadIdx.x;
  const int wave = tid >> 6, lane = tid & 63;
  const int l15 = lane & 15, g16 = lane >> 4;
  const int gbase = t0*64 - 64;
  const bool edge = (tile == 0) || (tile == 5);
  const h16* w116h = (const h16*)w116;
  float4 rv[7];

  auto loadci = [&](int ci) {
    const float* cb = cond + (size_t)(b*128 + ci)*TLEN;
    if (!edge) {
      #pragma unroll
      for (int r = 0; r < 6; ++r) rv[r] = F4(cb + gbase + 4*(tid + 256*r));
      if (tid < 16) rv[6] = F4(cb + gbase + 6144 + 4*tid);
    } else {
      #pragma unroll
      for (int r = 0; r < 7; ++r) {
        if (r < 6 || tid < 16) {
          int q = (r < 6) ? (tid + 256*r) : (1536 + tid);
          int g0 = gbase + 4*q;
          float4 v;
          v.x = (g0   >= 0 && g0   < TLEN) ? cb[g0]   : 0.f;
          v.y = (g0+1 >= 0 && g0+1 < TLEN) ? cb[g0+1] : 0.f;
          v.z = (g0+2 >= 0 && g0+2 < TLEN) ? cb[g0+2] : 0.f;
          v.w = (g0+3 >= 0 && g0+3 < TLEN) ? cb[g0+3] : 0.f;
          rv[r] = v;
        }
      }
    }
  };
  auto writeci = [&](int buf) {
    #pragma unroll
    for (int r = 0; r < 7; ++r) {
      if (r < 6 || tid < 16) {
        int q = (r < 6) ? (tid + 256*r) : (1536 + tid);
        int s2 = 2*q;
        int ph = s2 ^ (((s2 >> 5) & 7) << 2);
        uint2 pr;
        pr.x = (u32)pkh(rv[r].x) | ((u32)pkh(rv[r].y) << 16);
        pr.y = (u32)pkh(rv[r].z) | ((u32)pkh(rv[r].w) << 16);
        *reinterpret_cast<uint2*>(&segu[buf][ph]) = pr;
      }
    }
  };

  loadci(kc*16);
  writeci(0);
  __syncthreads();
  f32x4 acc[4][6] = {};
  for (int cl = 0; cl < 16; ++cl) {
    if (cl < 15) loadci(kc*16 + cl + 1);            // T14: issue early
    const u32* sbu = segu[cl & 1];
    const h16* wb = w116h + (size_t)(kc*16 + cl)*32768;
    #pragma unroll
    for (int ks = 0; ks < 4; ++ks) {
      half8 Bf[6];
      #pragma unroll
      for (int nt = 0; nt < 6; ++nt) {
        int s2 = 32*(nt*16 + l15) + 16*ks + 4*g16;
        int ph = s2 ^ (((s2 >> 5) & 7) << 2);
        Bf[nt] = *(const half8*)&sbu[ph];
      }
      #pragma unroll
      for (int mi = 0; mi < 4; ++mi) {
        const int co = (wave*4 + mi)*16 + l15;
        half8 Af = *(const half8*)(wb + co*128 + ks*32 + g16*8);
        #pragma unroll
        for (int nt = 0; nt < 6; ++nt)
          acc[mi][nt] = __builtin_amdgcn_mfma_f32_16x16x32_f16(Af, Bf[nt], acc[mi][nt], 0,0,0);
      }
    }
    __syncthreads();
    if (cl < 15) writeci((cl + 1) & 1);             // T14: write late
    __syncthreads();
  }
  h16* hp = (h16*)hpart;
  #pragma unroll
  for (int mi = 0; mi < 4; ++mi) {
    const int co0 = (wave*4 + mi)*16 + g16*4;
    #pragma unroll
    for (int nt = 0; nt < 6; ++nt) {
      int t = t0 + nt*16 + l15;                     // always < 513
      half4 v;
      v[0]=(h16)acc[mi][nt][0]; v[1]=(h16)acc[mi][nt][1];
      v[2]=(h16)acc[mi][nt][2]; v[3]=(h16)acc[mi][nt][3];
      *(half4*)(hp + ((size_t)(kc*8 + b)*NFR + t)*256 + co0) = v;
    }
  }
}

// reduce 8 partials + b1 -> hT16[b][t][c] fp16, chunk-swizzled (c/8 ^ (t&7))
__launch_bounds__(256)
__global__ void dfc_hred(const u16* __restrict__ hpart, const float* __restrict__ b1,
                         u16* __restrict__ hT16) {
  int idx = blockIdx.x*256 + threadIdx.x;            // < 131328
  int b = idx / 16416, r = idx % 16416;
  int t = r >> 5, cc = r & 31;
  float s[8];
  float4 ba = F4(&b1[cc*8]), bb = F4(&b1[cc*8 + 4]);
  s[0]=ba.x; s[1]=ba.y; s[2]=ba.z; s[3]=ba.w; s[4]=bb.x; s[5]=bb.y; s[6]=bb.z; s[7]=bb.w;
  const h16* hp = (const h16*)hpart;
  #pragma unroll
  for (int kc = 0; kc < 8; ++kc) {
    half8 hv = *(const half8*)(hp + ((size_t)(kc*8 + b)*NFR + t)*256 + cc*8);
    #pragma unroll
    for (int j = 0; j < 8; ++j) s[j] += (float)hv[j];
  }
  half8 o;
  #pragma unroll
  for (int j = 0; j < 8; ++j) o[j] = (h16)s[j];
  *(half8*)((h16*)hT16 + ((size_t)b*TP + t)*256 + ((cc ^ (t & 7)) << 3)) = o;
}

// stft v3 (MFMA): X[c=p*68+fb][t] = Tst[144x128] * frames[128k x 96t]
// grid (6 tiles, 128 rows); same Toeplitz staging as conv1 (reflect pad).
__launch_bounds__(256)
__global__ void dfc_stft(const float* __restrict__ x, const float* __restrict__ wsp,
                         u16* __restrict__ X16) {
  __shared__ __align__(16) u32 winu[3104];
  const int tile = blockIdx.x, row = blockIdx.y;
  const int t0 = (tile < 5) ? tile*96 : 417;
  const int tid = threadIdx.x;
  const int wave = tid >> 6, lane = tid & 63;
  const int wm = wave >> 1, wn = wave & 1;
  const int l15 = lane & 15, g16 = lane >> 4;
  const int gbase = t0*64 - 64;
  const bool edge = (tile == 0) || (tile == 5);
  const float* xb = x + (size_t)row*TLEN;

  #pragma unroll
  for (int r = 0; r < 7; ++r) {
    if (r < 6 || tid < 16) {
      int q = (r < 6) ? (tid + 256*r) : (1536 + tid);
      float4 v;
      if (!edge) {
        v = F4(xb + gbase + 4*q);
      } else {
        int g0 = gbase + 4*q;
        float e[4];
        #pragma unroll
        for (int j = 0; j < 4; ++j) {
          int g = g0 + j;
          int sidx = (g < 0) ? -g : ((g >= TLEN) ? (2*TLEN - 2 - g) : g);
          e[j] = xb[sidx];
        }
        v.x = e[0]; v.y = e[1]; v.z = e[2]; v.w = e[3];
      }
      int s2 = 2*q;
      int ph = s2 ^ (((s2 >> 5) & 7) << 2);
      uint2 pr;
      pr.x = (u32)pkh(v.x) | ((u32)pkh(v.y) << 16);
      pr.y = (u32)pkh(v.z) | ((u32)pkh(v.w) << 16);
      *reinterpret_cast<uint2*>(&winu[ph]) = pr;
    }
  }
  __syncthreads();
  const h16* Ts = (const h16*)(wsp + OFF_TST);
  f32x4 acc[5][3] = {};                              // wm0: mi 0..4, wm1: mi 4..8 (dup mi4 ok)
  #pragma unroll
  for (int ks = 0; ks < 4; ++ks) {
    half8 Bf[3];
    #pragma unroll
    for (int nt = 0; nt < 3; ++nt) {
      int tl = (wn*3 + nt)*16 + l15;
      int s2 = 32*tl + 16*ks + 4*g16;
      int ph = s2 ^ (((s2 >> 5) & 7) << 2);
      Bf[nt] = *(const half8*)&winu[ph];
    }
    #pragma unroll
    for (int m = 0; m < 5; ++m) {
      int mi = wm*4 + m;
      half8 Af = *(const half8*)(Ts + (size_t)(mi*16 + l15)*128 + ks*32 + g16*8);
      #pragma unroll
      for (int nt = 0; nt < 3; ++nt)
        acc[m][nt] = __builtin_amdgcn_mfma_f32_16x16x32_f16(Af, Bf[nt], acc[m][nt], 0,0,0);
    }
  }
  h16* Xh = (h16*)X16;
  #pragma unroll
  for (int m = 0; m < 5; ++m) {
    int c0 = (wm*4 + m)*16 + g16*4;
    if (c0 < 136) {
      #pragma unroll
      for (int nt = 0; nt < 3; ++nt) {
        int t = t0 + (wn*3 + nt)*16 + l15;          // always <= 512
        half4 v;
        v[0]=(h16)acc[m][nt][0]; v[1]=(h16)acc[m][nt][1];
        v[2]=(h16)acc[m][nt][2]; v[3]=(h16)acc[m][nt][3];
        *(half4*)(Xh + ((size_t)row*TP + t)*136 + c0) = v;
      }
    }
  }
}

// conv2y v3: B (hT16, K=256) lane-resident in 96 VGPRs reused across all 16 i;
// LDS = A-only 4-buffer (64KB), staged 2 steps ahead, vmcnt(8), 1 barrier/step.
__launch_bounds__(256, 2)
__global__ void dfc_conv2y(const u16* __restrict__ w216, const u16* __restrict__ hT16,
                           const u16* __restrict__ b2p, const u16* __restrict__ X16,
                           u16* __restrict__ Y16) {
  __shared__ __align__(16) char Al[4][16384];
  const int flat = (blockIdx.z*16 + blockIdx.y)*6 + blockIdx.x;
  const int b  = flat & 7;
  const int r2 = flat >> 3;
  const int o  = r2 / 6;
  const int t0 = (r2 - o*6) * 96;
  const int tid = threadIdx.x;
  const int wave = tid >> 6, lane = tid & 63;
  const int wp = wave >> 1, wn = wave & 1;
  const int l15 = lane & 15, g16 = lane >> 4;
  const int lrow8 = lane >> 3, lcol = (lane & 7)*16;
  const char* wb = (const char*)w216;

  // B preload: 24 half8 (3 nt x 8 ks), chunk-deswizzled from hT16
  half8 Breg[3][8];
  #pragma unroll
  for (int nt = 0; nt < 3; ++nt) {
    int t = t0 + wn*48 + nt*16 + l15;
    const h16* hrow = (const h16*)hT16 + ((size_t)b*TP + t)*256;
    #pragma unroll
    for (int ks = 0; ks < 8; ++ks)
      Breg[nt][ks] = *(const half8*)(hrow + (((ks*4 + g16) ^ (t & 7)) << 3));
  }

  auto stageA = [&](int s, char* dst) {
    const int i = s >> 2, kk = s & 3;
    const int rb0 = (o*16 + i)*65, rb1 = (256 + o*16 + i)*65;
    #pragma unroll
    for (int j = 0; j < 4; ++j) {
      int rr = wave*32 + j*8 + lrow8;
      int wrow = (rr < 64) ? (rb0 + rr) : (rb1 + (rr - 64));
      GLDS(wb + (((size_t)wrow*256 + kk*64) << 1) + lcol, dst + (wave*32 + j*8)*128);
    }
  };

  stageA(0, Al[0]);
  stageA(1, Al[1]);
  __syncthreads();

  f32x4 yac[4][3] = {};
  f32x4 fac[4][3];
  const h16* b2ph = (const h16*)b2p;
  for (int i = 0; i < 16; ++i) {
    #pragma unroll
    for (int mi = 0; mi < 4; ++mi) {
      half4 bh = *(const half4*)(b2ph + (size_t)((o*16 + i)*2 + wp)*64 + mi*16 + g16*4);
      #pragma unroll
      for (int nt = 0; nt < 3; ++nt) {
        fac[mi][nt][0] = (float)bh[0]; fac[mi][nt][1] = (float)bh[1];
        fac[mi][nt][2] = (float)bh[2]; fac[mi][nt][3] = (float)bh[3];
      }
    }
    #pragma unroll
    for (int kk = 0; kk < 4; ++kk) {
      const int s = i*4 + kk;
      if (s < 62) stageA(s + 2, Al[(kk + 2) & 3]);
      if (s < 62)      { asm volatile("s_waitcnt vmcnt(8)" ::: "memory"); }
      else if (s == 62){ asm volatile("s_waitcnt vmcnt(4)" ::: "memory"); }
      else             { asm volatile("s_waitcnt vmcnt(0)" ::: "memory"); }
      __builtin_amdgcn_s_barrier();
      __builtin_amdgcn_sched_barrier(0);
      const char* Ab = Al[kk];
      __builtin_amdgcn_s_setprio(1);
      #pragma unroll
      for (int ks2 = 0; ks2 < 2; ++ks2) {
        half8 Af[4];
        #pragma unroll
        for (int mi = 0; mi < 4; ++mi) {
          int rr = wp*64 + mi*16 + l15;
          Af[mi] = *(const half8*)(Ab + rr*128 + (((ks2*4 + g16) ^ (rr & 7)) << 4));
        }
        #pragma unroll
        for (int mi = 0; mi < 4; ++mi)
          #pragma unroll
          for (int nt = 0; nt < 3; ++nt)
            fac[mi][nt] = __builtin_amdgcn_mfma_f32_16x16x32_f16(Af[mi], Breg[nt][kk*2 + ks2], fac[mi][nt], 0,0,0);
      }
      __builtin_amdgcn_s_setprio(0);
    }
    // epilogue: yac += fac * X_i
    const h16* Xrow = (const h16*)X16 + (size_t)(b*16 + i)*TP*136;
    #pragma unroll
    for (int mi = 0; mi < 4; ++mi) {
      int fb0 = mi*16 + g16*4;
      #pragma unroll
      for (int nt = 0; nt < 3; ++nt) {
        int t = t0 + wn*48 + nt*16 + l15;
        half4 xv = *(const half4*)(Xrow + (size_t)t*136 + wp*68 + fb0);
        yac[mi][nt][0] += fac[mi][nt][0]*(float)xv[0];
        yac[mi][nt][1] += fac[mi][nt][1]*(float)xv[1];
        yac[mi][nt][2] += fac[mi][nt][2]*(float)xv[2];
        yac[mi][nt][3] += fac[mi][nt][3]*(float)xv[3];
      }
    }
  }
  h16* Yh = (h16*)Y16;
  #pragma unroll
  for (int mi = 0; mi < 4; ++mi) {
    int fb0 = mi*16 + g16*4;
    #pragma unroll
    for (int nt = 0; nt < 3; ++nt) {
      int t = t0 + wn*48 + nt*16 + l15;
      if (t < NFR) {
        half4 v;
        v[0]=(h16)yac[mi][nt][0]; v[1]=(h16)yac[mi][nt][1];
        v[2]=(h16)yac[mi][nt][2]; v[3]=(h16)yac[mi][nt][3];
        *(half4*)(Yh + ((size_t)(b*16 + o)*NFR + t)*136 + wp*68 + fb0) = v;
      }
    }
  }
}

// fb=64 (Nyquist) slice
__launch_bounds__(256)
__global__ void dfc_edge(const float* __restrict__ w2, const float* __restrict__ b2,
                         const u16* __restrict__ hT16, const u16* __restrict__ X16,
                         u16* __restrict__ Y16) {
  __shared__ float Wl[8192];
  __shared__ float b2l[32];
  const int o = blockIdx.x, b = blockIdx.y, tc = blockIdx.z, tid = threadIdx.x;
  for (int idx = tid; idx < 8192; idx += 256) {
    int pi = idx >> 8, c = idx & 255;
    int p = pi >> 4, i = pi & 15;
    Wl[idx] = w2[(size_t)(((p*16 + o)*16 + i)*65 + 64)*256 + c];
  }
  if (tid < 32) {
    int p = tid >> 4, i = tid & 15;
    b2l[tid] = b2[(size_t)((p*16 + o)*16 + i)*65 + 64];
  }
  __syncthreads();
  const h16* hh = (const h16*)hT16;
  const h16* Xh = (const h16*)X16;
  h16* Yh = (h16*)Y16;
  for (int t = tc*256 + tid; t < NFR; t += 512) {
    int key = t & 7;
    float facc[32];
    #pragma unroll
    for (int pi = 0; pi < 32; ++pi) facc[pi] = b2l[pi];
    const h16* hrow = hh + ((size_t)b*TP + t)*256;
    for (int cc = 0; cc < 32; ++cc) {
      half8 hv = *(const half8*)(hrow + ((cc ^ key) << 3));
      float h0=(float)hv[0], h1=(float)hv[1], h2=(float)hv[2], h3=(float)hv[3];
      float h4=(float)hv[4], h5=(float)hv[5], h6=(float)hv[6], h7=(float)hv[7];
      #pragma unroll
      for (int pi = 0; pi < 32; ++pi) {
        const float* wr = &Wl[pi*256 + cc*8];
        facc[pi] += wr[0]*h0 + wr[1]*h1 + wr[2]*h2 + wr[3]*h3
                  + wr[4]*h4 + wr[5]*h5 + wr[6]*h6 + wr[7]*h7;
      }
    }
    float y0 = 0.f, y1 = 0.f;
    #pragma unroll
    for (int pi = 0; pi < 32; ++pi) {
      int p = pi >> 4, i = pi & 15;
      float xv = (float)Xh[((size_t)(b*16 + i)*TP + t)*136 + p*68 + 64];
      if (p == 0) y0 += facc[pi]*xv; else y1 += facc[pi]*xv;
    }
    Yh[((size_t)(b*16 + o)*NFR + t)*136 + 0*68 + 64] = (h16)y0;
    Yh[((size_t)(b*16 + o)*NFR + t)*136 + 1*68 + 64] = (h16)y1;
  }
}

// iSTFT: MFMA fr = Tist[128k x 136c] * Yl[136c x t], OLA in LDS, invden in table
__launch_bounds__(256)
__global__ void dfc_istft(const u16* __restrict__ Y16, const float* __restrict__ wsp,
                          const float* __restrict__ bias, float* __restrict__ out) {
  __shared__ __align__(16) char YL[80*336];        // 26880 B; reused as outT[64][68] f32
  const int u = blockIdx.x, row = blockIdx.y, tid = threadIdx.x;
  const int wave = tid >> 6, lane = tid & 63;
  const int l15 = lane & 15, g16 = lane >> 4;
  for (int i = tid; i < 1680; i += 256) ((float4*)YL)[i] = float4{0.f,0.f,0.f,0.f};
  __syncthreads();
  const char* Yb = (const char*)Y16 + ((size_t)row*NFR + u*64)*272;
  for (int ch = tid; ch < 1105; ch += 256) {       // 65 rows x 17 chunks
    int tl = ch / 17, cc = ch - tl*17;
    float4 v = F4(Yb + (size_t)tl*272 + cc*16);
    *(float4*)(YL + tl*336 + cc*16) = v;
  }
  __syncthreads();
  const h16* Ti = (const h16*)(wsp + OFF_TI);
  f32x4 acc[2][5] = {};
  #pragma unroll
  for (int ks = 0; ks < 5; ++ks) {
    half8 Af[2];
    #pragma unroll
    for (int m = 0; m < 2; ++m)
      Af[m] = *(const half8*)(Ti + (size_t)((wave*2 + m)*16 + l15)*160 + ks*32 + g16*8);
    #pragma unroll
    for (int nt = 0; nt < 5; ++nt) {
      half8 Bf = *(const half8*)(YL + (nt*16 + l15)*336 + ks*64 + g16*16);
      acc[0][nt] = __builtin_amdgcn_mfma_f32_16x16x32_f16(Af[0], Bf, acc[0][nt], 0,0,0);
      acc[1][nt] = __builtin_amdgcn_mfma_f32_16x16x32_f16(Af[1], Bf, acc[1][nt], 0,0,0);
    }
  }
  __syncthreads();
  float* outT = (float*)YL;                        // [64][68]
  if (wave >= 2) {                                 // k>=64: out[t][k-64] = val
    #pragma unroll
    for (int m = 0; m < 2; ++m) {
      int j0 = (wave*2 + m - 4)*16 + g16*4;
      #pragma unroll
      for (int nt = 0; nt < 4; ++nt) {
        int t = nt*16 + l15;
        *(f32x4*)&outT[t*68 + j0] = acc[m][nt];
      }
    }
  }
  __syncthreads();
  if (wave < 2) {                                  // k<64: out[t-1][k] += val
    #pragma unroll
    for (int m = 0; m < 2; ++m) {
      int j0 = (wave*2 + m)*16 + g16*4;
      #pragma unroll
      for (int nt = 0; nt < 5; ++nt) {
        int t = nt*16 + l15;
        if (t >= 1 && t <= 64) {
          f32x4 v = *(f32x4*)&outT[(t-1)*68 + j0];
          v[0] += acc[m][nt][0]; v[1] += acc[m][nt][1];
          v[2] += acc[m][nt][2]; v[3] += acc[m][nt][3];
          *(f32x4*)&outT[(t-1)*68 + j0] = v;
        }
      }
    }
  }
  __syncthreads();
  const float bv = bias[row & 15];
  float* og = out + (size_t)row*TLEN + (size_t)u*4096;
  #pragma unroll
  for (int r = 0; r < 4; ++r) {
    int fi = tid + 256*r;
    int sg = fi >> 4, jj = (fi & 15)*4;
    float4 v = *(float4*)&outT[sg*68 + jj];
    float4 w{v.x + bv, v.y + bv, v.z + bv, v.w + bv};
    *(float4*)(og + sg*64 + jj) = w;
  }
}

extern "C" void kernel_launch(void* const* d_in, const int* in_sizes, int n_in,
                              void* d_out, int out_size, void* d_ws, size_t ws_size,
                              hipStream_t stream) {
  (void)in_sizes; (void)n_in; (void)out_size; (void)ws_size;
  const float* x    = (const float*)d_in[0];
  const float* cond = (const float*)d_in[1];
  const float* w1   = (const float*)d_in[2];
  const float* b1   = (const float*)d_in[3];
  const float* w2   = (const float*)d_in[4];
  const float* b2   = (const float*)d_in[5];
  const float* bias = (const float*)d_in[6];
  float* ws  = (float*)d_ws;
  float* out = (float*)d_out;
  u16* R     = (u16*)(ws + OFF_R);      // hpart then w216
  u16* b2p   = (u16*)(ws + OFF_B2P);
  u16* hT16  = (u16*)(ws + OFF_HT);
  u16* X16   = (u16*)(ws + OFF_X16);
  u16* Y16   = (u16*)(ws + OFF_Y16);
  u16* w116  = (u16*)(ws + OFF_W116);

  hipMemsetAsync(hT16, 0, (size_t)8*TP*256*2, stream);
  hipMemsetAsync(X16, 0, (size_t)128*TP*136*2, stream);
  dfc_tables<<<dim3(1), dim3(256), 0, stream>>>(ws);
  dfc_prep_w1<<<dim3(2048), dim3(256), 0, stream>>>(w1, w116);
  dfc_conv1<<<dim3(6, 8, 8), dim3(256), 0, stream>>>(cond, w116, R);
  dfc_hred<<<dim3(513), dim3(256), 0, stream>>>(R, b1, hT16);
  dfc_prep_w2<<<dim3(4160), dim3(256), 0, stream>>>(w2, R);
  dfc_prep_b2<<<dim3(128), dim3(256), 0, stream>>>(b2, b2p);
  dfc_stft<<<dim3(6, 128), dim3(256), 0, stream>>>(x, ws, X16);
  dfc_conv2y<<<dim3(6, 16, 8), dim3(256), 0, stream>>>(R, hT16, b2p, X16, Y16);
  dfc_edge<<<dim3(16, 8, 2), dim3(256), 0, stream>>>(w2, b2, hT16, X16, Y16);
  dfc_istft<<<dim3(8, 128), dim3(256), 0, stream>>>(Y16, ws, bias, out);
}

// Round 9
// 512.681 us; speedup vs baseline: 7.9976x; 1.0038x over previous
//
#include <hip/hip_runtime.h>
#include <math.h>

#define TLEN 32768
#define NFR  513
#define TP   576          // padded frame count
#define PI_F 3.14159265358979323846f

typedef unsigned short u16;
typedef unsigned int   u32;
typedef _Float16 h16;
typedef h16  half8  __attribute__((ext_vector_type(8)));
typedef h16  half4  __attribute__((ext_vector_type(4)));
typedef float f32x4 __attribute__((ext_vector_type(4)));

// float-unit offsets in workspace
#define OFF_TST  0         // Tst h16 [144][128]: stft DFT table (window folded)
#define OFF_TI   9216      // Tist h16 [128][160]: istft table, invden folded
#define OFF_B2P  19456     // b2p h16 [512][64]: b2 repack [(o,i,p)][fb]
#define OFF_R    35840     // hpart h16 [64][513][256] THEN w216 h16 [33280][256]
#define OFF_HT   4295680   // hT16 h16 [8][576][256], chunk-swizzled
#define OFF_X16  4885504   // X16 h16 [128][576][136]
#define OFF_Y16  9899008   // Y16 h16 [128][513][136]
#define OFF_W116 14364160  // w116s h16 [128ci][2 half][256co x 64k swizzled]
// end: 16,461,312 floats = 65.8 MB

#define F4(p) (*reinterpret_cast<const float4*>(p))
#define GLDS(gsrc, ldst) __builtin_amdgcn_global_load_lds( \
    (const __attribute__((address_space(1))) void*)(gsrc),  \
    (__attribute__((address_space(3))) void*)(ldst), 16, 0, 0)

__device__ __forceinline__ u16 pkh(float v) { return __builtin_bit_cast(u16, (h16)v); }

__global__ void dfc_tables(float* __restrict__ ws) {
  int tid = threadIdx.x;
  // Tst[c][k], c = p*68+fb: stft DFT rows (pads zero)
  u16* Ts = (u16*)(ws + OFF_TST);
  for (int idx = tid; idx < 144*128; idx += 256) {
    int c = idx >> 7, k = idx & 127;
    float v = 0.0f;
    if (c < 136) {
      int p = c / 68, fb = c - p*68;
      if (fb <= 64) {
        float wk = 0.5f*(1.0f - cosf(2.0f*PI_F*(float)k/128.0f));
        float ang = 2.0f*PI_F*(float)((fb*k) & 127)/128.0f;
        v = (p == 0) ? wk*cosf(ang) : -wk*sinf(ang);
      }
    }
    Ts[idx] = pkh(v);
  }
  // Tist[k][c]: istft table, invden folded; rows padded to 160
  u16* Ti = (u16*)(ws + OFF_TI);
  for (int idx = tid; idx < 128*160; idx += 256) {
    int k = idx / 160, c = idx - k*160;
    float v = 0.0f;
    if (c < 136) {
      int p = c / 68, fb = c - p*68;
      if (fb <= 64) {
        float wk = 0.5f*(1.0f - cosf(2.0f*PI_F*(float)k/128.0f));
        float cf = (fb == 0 || fb == 64) ? 1.0f : 2.0f;
        float sc = (1.0f/128.0f)*wk*cf;
        float ang = 2.0f*PI_F*(float)((fb*k) & 127)/128.0f;
        int j = k & 63;
        float w0 = 0.5f*(1.0f - cosf(2.0f*PI_F*(float)j/128.0f));
        float w1 = 0.5f*(1.0f - cosf(2.0f*PI_F*(float)(j+64)/128.0f));
        float inv = 1.0f/fmaxf(w0*w0 + w1*w1, 1e-11f);
        v = ((p == 0) ? sc*cosf(ang) : -sc*sinf(ang)) * inv;
      }
    }
    Ti[idx] = pkh(v);
  }
}

// w116s: per (ci, half): 16 KB h16 block [256co][64k], XOR-swizzled:
// h16 idx within block = co*64 + (((k8&7) ^ (co&7))<<3) + (k within 8)
__launch_bounds__(256)
__global__ void dfc_prep_w1(const float* __restrict__ w1, u16* __restrict__ w116) {
  int idx = blockIdx.x*256 + threadIdx.x;           // < 524288
  int k8 = idx & 15, rc = idx >> 4;
  int co = rc & 255, ci = rc >> 8;
  const float* src = w1 + ((size_t)(co*128 + ci)*128 + k8*8);
  float4 a = F4(src), b = F4(src + 4);
  half8 hv;
  hv[0]=(h16)a.x; hv[1]=(h16)a.y; hv[2]=(h16)a.z; hv[3]=(h16)a.w;
  hv[4]=(h16)b.x; hv[5]=(h16)b.y; hv[6]=(h16)b.z; hv[7]=(h16)b.w;
  size_t dst = (size_t)ci*32768 + (k8 >> 3)*16384
             + co*64 + ((((k8 & 7) ^ (co & 7))) << 3);
  *(half8*)((h16*)w116 + dst) = hv;
}

// w216[row][c] = fp16(w2[row][c]) with in-row chunk swizzle: chunk c/8 ^ (fb&7)
__launch_bounds__(256)
__global__ void dfc_prep_w2(const float* __restrict__ w2, u16* __restrict__ w216) {
  int idx = blockIdx.x*256 + threadIdx.x;           // < 1064960
  int cc = idx & 31, r = idx >> 5;
  int fb = r % 65;
  const float* src = w2 + (size_t)r*256 + cc*8;
  float4 a = F4(src), b = F4(src + 4);
  half8 hv;
  hv[0]=(h16)a.x; hv[1]=(h16)a.y; hv[2]=(h16)a.z; hv[3]=(h16)a.w;
  hv[4]=(h16)b.x; hv[5]=(h16)b.y; hv[6]=(h16)b.z; hv[7]=(h16)b.w;
  *(half8*)((h16*)w216 + (size_t)r*256 + ((cc ^ (fb & 7)) << 3)) = hv;
}

// b2p[((o*16+i)*2+p)*64 + fb] = fp16(b2[((p*16+o)*16+i)*65 + fb]), fb<64
__launch_bounds__(256)
__global__ void dfc_prep_b2(const float* __restrict__ b2, u16* __restrict__ b2p) {
  int idx = blockIdx.x*256 + threadIdx.x;           // < 32768
  int fb = idx & 63, r = idx >> 6;
  int p = r & 1, oi = r >> 1, o = oi >> 4, i = oi & 15;
  ((h16*)b2p)[idx] = (h16)b2[(size_t)((p*16 + o)*16 + i)*65 + fb];
}

// conv1 v7.2: both operands via global_load_lds, counted vmcnt ring-2, 8 waves,
// 256co x 64t tile, 32 half-ci phases. grid (9,8,8); kc = linear%8.
// FIX vs v7.1: (a) B staging covers all 1040 chunks (was 272);
//              (b) second B chunk swizzled independently ((L0+16)^swz, not (L0^swz)+16).
#define CV1_A 32768
#define CV1_B 17408        // 4352 f32 window (used 4160)
__launch_bounds__(512, 2)
__global__ void dfc_conv1(const float* __restrict__ cond, const u16* __restrict__ w116,
                          u16* __restrict__ hpart) {
  extern __shared__ __align__(16) char LDS[];       // 2*32768 + 2*17408 = 100352 B
  const int flat = (blockIdx.z*8 + blockIdx.y)*9 + blockIdx.x;
  const int kc = flat & 7;
  const int rest = flat >> 3;                       // 0..71
  const int b = rest / 9, tile = rest - b*9;
  const int t0 = tile*64;
  const int tid = threadIdx.x;
  const int wave = tid >> 6, lane = tid & 63;
  const int w4 = wave & 3;
  const int l15 = lane & 15, g16 = lane >> 4;
  const int gbase4 = (t0*64 - 64)*4;
  const bool edge = (tile == 0) || (tile >= 7);
  const char* wbB   = (const char*)w116 + (size_t)kc*16*65536;
  const char* condB = (const char*)cond + (size_t)(b*128 + kc*16)*TLEN*4;

  // B staging: 1040 chunks; subgroup w4 handles 260 (4x64 + 4@lane<4); waves 4-7 dup.
  int bOff[5]; bool bOk[5];
  #pragma unroll
  for (int r = 0; r < 5; ++r) {
    int c = 260*w4 + r*64 + lane;
    int cs = c ^ ((c >> 4) & 7);                    // inverse of read swizzle
    bOff[r] = gbase4 + 16*cs;
    bool act = (r < 4) || (lane < 4);
    bOk[r] = act && (bOff[r] >= 0) && (bOff[r] < TLEN*4);
  }

  { // pre-zero B slots (masked/pad chunks stay zero)
    float* bz = (float*)(LDS + 2*CV1_A);
    for (int i = tid; i < 2*4352; i += 512) bz[i] = 0.0f;
  }
  __syncthreads();

  auto stageA = [&](int ci, int h, int slot) {      // 4 GLDS/wave
    const char* src = wbB + (size_t)ci*65536 + h*32768 + wave*4096 + lane*16;
    char* dst = LDS + slot*CV1_A + wave*4096;
    GLDS(src,        dst);
    GLDS(src + 1024, dst + 1024);
    GLDS(src + 2048, dst + 2048);
    GLDS(src + 3072, dst + 3072);
  };
  auto stageB = [&](int ci, int slot) {             // 5 GLDS/wave
    const char* src = condB + (size_t)ci*TLEN*4;
    char* base = LDS + 2*CV1_A + slot*CV1_B;
    #pragma unroll
    for (int r = 0; r < 5; ++r)
      if (bOk[r]) GLDS(src + bOff[r], base + 16*(260*w4 + 64*r));
  };

  stageA(0, 0, 0); stageB(0, 0);                    // phase 0 (9 loads/wave)
  stageA(0, 1, 1);                                  // phase 1 (4 loads/wave)

  f32x4 acc[2][4] = {};
  for (int p = 0; p < 32; ++p) {
    const int ci = p >> 1, h = p & 1;
    const char* Ab = LDS + (p & 1)*CV1_A;
    const char* Bb = LDS + 2*CV1_A + (ci & 1)*CV1_B;
    if (edge || p == 31) { asm volatile("s_waitcnt vmcnt(0)" ::: "memory"); }
    else if (p & 1)      { asm volatile("s_waitcnt vmcnt(9)" ::: "memory"); }
    else                 { asm volatile("s_waitcnt vmcnt(4)" ::: "memory"); }
    __builtin_amdgcn_s_barrier();
    __builtin_amdgcn_sched_barrier(0);
    #pragma unroll
    for (int ks = 0; ks < 2; ++ks) {
      half8 Bf[4];
      #pragma unroll
      for (int nt = 0; nt < 4; ++nt) {
        int tl = nt*16 + l15;
        int L0 = 4*(64*tl + 64*h + 32*ks + 8*g16);
        int sw = ((L0 >> 8) & 7) << 4;
        float4 v0 = F4(Bb + (L0 ^ sw));
        float4 v1 = F4(Bb + ((L0 + 16) ^ sw));      // independent swizzle (FIX b)
        half8 hv;
        hv[0]=(h16)v0.x; hv[1]=(h16)v0.y; hv[2]=(h16)v0.z; hv[3]=(h16)v0.w;
        hv[4]=(h16)v1.x; hv[5]=(h16)v1.y; hv[6]=(h16)v1.z; hv[7]=(h16)v1.w;
        Bf[nt] = hv;
      }
      #pragma unroll
      for (int mi = 0; mi < 2; ++mi) {
        int co = wave*32 + mi*16 + l15;
        half8 Af = *(const half8*)(Ab + co*128 + (((ks*4 + g16) ^ (co & 7)) << 4));
        #pragma unroll
        for (int nt = 0; nt < 4; ++nt)
          acc[mi][nt] = __builtin_amdgcn_mfma_f32_16x16x32_f16(Af, Bf[nt], acc[mi][nt], 0,0,0);
      }
    }
    __builtin_amdgcn_s_barrier();
    if (p + 2 < 32) {
      const int p2 = p + 2, ci2 = p2 >> 1, h2 = p2 & 1;
      stageA(ci2, h2, p2 & 1);
      if (h2 == 0) stageB(ci2, ci2 & 1);
    }
  }
  h16* hp = (h16*)hpart;
  #pragma unroll
  for (int mi = 0; mi < 2; ++mi) {
    const int co0 = wave*32 + mi*16 + g16*4;
    #pragma unroll
    for (int nt = 0; nt < 4; ++nt) {
      int t = t0 + nt*16 + l15;
      if (t < NFR) {
        half4 v;
        v[0]=(h16)acc[mi][nt][0]; v[1]=(h16)acc[mi][nt][1];
        v[2]=(h16)acc[mi][nt][2]; v[3]=(h16)acc[mi][nt][3];
        *(half4*)(hp + ((size_t)(kc*8 + b)*NFR + t)*256 + co0) = v;
      }
    }
  }
}

// reduce 8 partials + b1 -> hT16[b][t][c] fp16, chunk-swizzled (c/8 ^ (t&7))
__launch_bounds__(256)
__global__ void dfc_hred(const u16* __restrict__ hpart, const float* __restrict__ b1,
                         u16* __restrict__ hT16) {
  int idx = blockIdx.x*256 + threadIdx.x;            // < 131328
  int b = idx / 16416, r = idx % 16416;
  int t = r >> 5, cc = r & 31;
  float s[8];
  float4 ba = F4(&b1[cc*8]), bb = F4(&b1[cc*8 + 4]);
  s[0]=ba.x; s[1]=ba.y; s[2]=ba.z; s[3]=ba.w; s[4]=bb.x; s[5]=bb.y; s[6]=bb.z; s[7]=bb.w;
  const h16* hp = (const h16*)hpart;
  #pragma unroll
  for (int kc = 0; kc < 8; ++kc) {
    half8 hv = *(const half8*)(hp + ((size_t)(kc*8 + b)*NFR + t)*256 + cc*8);
    #pragma unroll
    for (int j = 0; j < 8; ++j) s[j] += (float)hv[j];
  }
  half8 o;
  #pragma unroll
  for (int j = 0; j < 8; ++j) o[j] = (h16)s[j];
  *(half8*)((h16*)hT16 + ((size_t)b*TP + t)*256 + ((cc ^ (t & 7)) << 3)) = o;
}

// stft v3 (MFMA): X[c=p*68+fb][t] = Tst[144x128] * frames[128k x 96t]
__launch_bounds__(256)
__global__ void dfc_stft(const float* __restrict__ x, const float* __restrict__ wsp,
                         u16* __restrict__ X16) {
  __shared__ __align__(16) u32 winu[3104];
  const int tile = blockIdx.x, row = blockIdx.y;
  const int t0 = (tile < 5) ? tile*96 : 417;
  const int tid = threadIdx.x;
  const int wave = tid >> 6, lane = tid & 63;
  const int wm = wave >> 1, wn = wave & 1;
  const int l15 = lane & 15, g16 = lane >> 4;
  const int gbase = t0*64 - 64;
  const bool edge = (tile == 0) || (tile == 5);
  const float* xb = x + (size_t)row*TLEN;

  #pragma unroll
  for (int r = 0; r < 7; ++r) {
    if (r < 6 || tid < 16) {
      int q = (r < 6) ? (tid + 256*r) : (1536 + tid);
      float4 v;
      if (!edge) {
        v = F4(xb + gbase + 4*q);
      } else {
        int g0 = gbase + 4*q;
        float e[4];
        #pragma unroll
        for (int j = 0; j < 4; ++j) {
          int g = g0 + j;
          int sidx = (g < 0) ? -g : ((g >= TLEN) ? (2*TLEN - 2 - g) : g);
          e[j] = xb[sidx];
        }
        v.x = e[0]; v.y = e[1]; v.z = e[2]; v.w = e[3];
      }
      int s2 = 2*q;
      int ph = s2 ^ (((s2 >> 5) & 7) << 2);
      uint2 pr;
      pr.x = (u32)pkh(v.x) | ((u32)pkh(v.y) << 16);
      pr.y = (u32)pkh(v.z) | ((u32)pkh(v.w) << 16);
      *reinterpret_cast<uint2*>(&winu[ph]) = pr;
    }
  }
  __syncthreads();
  const h16* Ts = (const h16*)(wsp + OFF_TST);
  f32x4 acc[5][3] = {};
  #pragma unroll
  for (int ks = 0; ks < 4; ++ks) {
    half8 Bf[3];
    #pragma unroll
    for (int nt = 0; nt < 3; ++nt) {
      int tl = (wn*3 + nt)*16 + l15;
      int s2 = 32*tl + 16*ks + 4*g16;
      int ph = s2 ^ (((s2 >> 5) & 7) << 2);
      Bf[nt] = *(const half8*)&winu[ph];
    }
    #pragma unroll
    for (int m = 0; m < 5; ++m) {
      int mi = wm*4 + m;
      half8 Af = *(const half8*)(Ts + (size_t)(mi*16 + l15)*128 + ks*32 + g16*8);
      #pragma unroll
      for (int nt = 0; nt < 3; ++nt)
        acc[m][nt] = __builtin_amdgcn_mfma_f32_16x16x32_f16(Af, Bf[nt], acc[m][nt], 0,0,0);
    }
  }
  h16* Xh = (h16*)X16;
  #pragma unroll
  for (int m = 0; m < 5; ++m) {
    int c0 = (wm*4 + m)*16 + g16*4;
    if (c0 < 136) {
      #pragma unroll
      for (int nt = 0; nt < 3; ++nt) {
        int t = t0 + (wn*3 + nt)*16 + l15;
        half4 v;
        v[0]=(h16)acc[m][nt][0]; v[1]=(h16)acc[m][nt][1];
        v[2]=(h16)acc[m][nt][2]; v[3]=(h16)acc[m][nt][3];
        *(half4*)(Xh + ((size_t)row*TP + t)*136 + c0) = v;
      }
    }
  }
}

// conv2y v3: B (hT16, K=256) lane-resident; LDS = A-only 4-buffer, vmcnt(8).
__launch_bounds__(256, 2)
__global__ void dfc_conv2y(const u16* __restrict__ w216, const u16* __restrict__ hT16,
                           const u16* __restrict__ b2p, const u16* __restrict__ X16,
                           u16* __restrict__ Y16) {
  __shared__ __align__(16) char Al[4][16384];
  const int flat = (blockIdx.z*16 + blockIdx.y)*6 + blockIdx.x;
  const int b  = flat & 7;
  const int r2 = flat >> 3;
  const int o  = r2 / 6;
  const int t0 = (r2 - o*6) * 96;
  const int tid = threadIdx.x;
  const int wave = tid >> 6, lane = tid & 63;
  const int wp = wave >> 1, wn = wave & 1;
  const int l15 = lane & 15, g16 = lane >> 4;
  const int lrow8 = lane >> 3, lcol = (lane & 7)*16;
  const char* wb = (const char*)w216;

  half8 Breg[3][8];
  #pragma unroll
  for (int nt = 0; nt < 3; ++nt) {
    int t = t0 + wn*48 + nt*16 + l15;
    const h16* hrow = (const h16*)hT16 + ((size_t)b*TP + t)*256;
    #pragma unroll
    for (int ks = 0; ks < 8; ++ks)
      Breg[nt][ks] = *(const half8*)(hrow + (((ks*4 + g16) ^ (t & 7)) << 3));
  }

  auto stageA = [&](int s, char* dst) {
    const int i = s >> 2, kk = s & 3;
    const int rb0 = (o*16 + i)*65, rb1 = (256 + o*16 + i)*65;
    #pragma unroll
    for (int j = 0; j < 4; ++j) {
      int rr = wave*32 + j*8 + lrow8;
      int wrow = (rr < 64) ? (rb0 + rr) : (rb1 + (rr - 64));
      GLDS(wb + (((size_t)wrow*256 + kk*64) << 1) + lcol, dst + (wave*32 + j*8)*128);
    }
  };

  stageA(0, Al[0]);
  stageA(1, Al[1]);
  __syncthreads();

  f32x4 yac[4][3] = {};
  f32x4 fac[4][3];
  const h16* b2ph = (const h16*)b2p;
  for (int i = 0; i < 16; ++i) {
    #pragma unroll
    for (int mi = 0; mi < 4; ++mi) {
      half4 bh = *(const half4*)(b2ph + (size_t)((o*16 + i)*2 + wp)*64 + mi*16 + g16*4);
      #pragma unroll
      for (int nt = 0; nt < 3; ++nt) {
        fac[mi][nt][0] = (float)bh[0]; fac[mi][nt][1] = (float)bh[1];
        fac[mi][nt][2] = (float)bh[2]; fac[mi][nt][3] = (float)bh[3];
      }
    }
    #pragma unroll
    for (int kk = 0; kk < 4; ++kk) {
      const int s = i*4 + kk;
      if (s < 62) stageA(s + 2, Al[(kk + 2) & 3]);
      if (s < 62)      { asm volatile("s_waitcnt vmcnt(8)" ::: "memory"); }
      else if (s == 62){ asm volatile("s_waitcnt vmcnt(4)" ::: "memory"); }
      else             { asm volatile("s_waitcnt vmcnt(0)" ::: "memory"); }
      __builtin_amdgcn_s_barrier();
      __builtin_amdgcn_sched_barrier(0);
      const char* Ab = Al[kk];
      __builtin_amdgcn_s_setprio(1);
      #pragma unroll
      for (int ks2 = 0; ks2 < 2; ++ks2) {
        half8 Af[4];
        #pragma unroll
        for (int mi = 0; mi < 4; ++mi) {
          int rr = wp*64 + mi*16 + l15;
          Af[mi] = *(const half8*)(Ab + rr*128 + (((ks2*4 + g16) ^ (rr & 7)) << 4));
        }
        #pragma unroll
        for (int mi = 0; mi < 4; ++mi)
          #pragma unroll
          for (int nt = 0; nt < 3; ++nt)
            fac[mi][nt] = __builtin_amdgcn_mfma_f32_16x16x32_f16(Af[mi], Breg[nt][kk*2 + ks2], fac[mi][nt], 0,0,0);
      }
      __builtin_amdgcn_s_setprio(0);
    }
    const h16* Xrow = (const h16*)X16 + (size_t)(b*16 + i)*TP*136;
    #pragma unroll
    for (int mi = 0; mi < 4; ++mi) {
      int fb0 = mi*16 + g16*4;
      #pragma unroll
      for (int nt = 0; nt < 3; ++nt) {
        int t = t0 + wn*48 + nt*16 + l15;
        half4 xv = *(const half4*)(Xrow + (size_t)t*136 + wp*68 + fb0);
        yac[mi][nt][0] += fac[mi][nt][0]*(float)xv[0];
        yac[mi][nt][1] += fac[mi][nt][1]*(float)xv[1];
        yac[mi][nt][2] += fac[mi][nt][2]*(float)xv[2];
        yac[mi][nt][3] += fac[mi][nt][3]*(float)xv[3];
      }
    }
  }
  h16* Yh = (h16*)Y16;
  #pragma unroll
  for (int mi = 0; mi < 4; ++mi) {
    int fb0 = mi*16 + g16*4;
    #pragma unroll
    for (int nt = 0; nt < 3; ++nt) {
      int t = t0 + wn*48 + nt*16 + l15;
      if (t < NFR) {
        half4 v;
        v[0]=(h16)yac[mi][nt][0]; v[1]=(h16)yac[mi][nt][1];
        v[2]=(h16)yac[mi][nt][2]; v[3]=(h16)yac[mi][nt][3];
        *(half4*)(Yh + ((size_t)(b*16 + o)*NFR + t)*136 + wp*68 + fb0) = v;
      }
    }
  }
}

// fb=64 (Nyquist) slice
__launch_bounds__(256)
__global__ void dfc_edge(const float* __restrict__ w2, const float* __restrict__ b2,
                         const u16* __restrict__ hT16, const u16* __restrict__ X16,
                         u16* __restrict__ Y16) {
  __shared__ float Wl[8192];
  __shared__ float b2l[32];
  const int o = blockIdx.x, b = blockIdx.y, tc = blockIdx.z, tid = threadIdx.x;
  for (int idx = tid; idx < 8192; idx += 256) {
    int pi = idx >> 8, c = idx & 255;
    int p = pi >> 4, i = pi & 15;
    Wl[idx] = w2[(size_t)(((p*16 + o)*16 + i)*65 + 64)*256 + c];
  }
  if (tid < 32) {
    int p = tid >> 4, i = tid & 15;
    b2l[tid] = b2[(size_t)((p*16 + o)*16 + i)*65 + 64];
  }
  __syncthreads();
  const h16* hh = (const h16*)hT16;
  const h16* Xh = (const h16*)X16;
  h16* Yh = (h16*)Y16;
  for (int t = tc*256 + tid; t < NFR; t += 512) {
    int key = t & 7;
    float facc[32];
    #pragma unroll
    for (int pi = 0; pi < 32; ++pi) facc[pi] = b2l[pi];
    const h16* hrow = hh + ((size_t)b*TP + t)*256;
    for (int cc = 0; cc < 32; ++cc) {
      half8 hv = *(const half8*)(hrow + ((cc ^ key) << 3));
      float h0=(float)hv[0], h1=(float)hv[1], h2=(float)hv[2], h3=(float)hv[3];
      float h4=(float)hv[4], h5=(float)hv[5], h6=(float)hv[6], h7=(float)hv[7];
      #pragma unroll
      for (int pi = 0; pi < 32; ++pi) {
        const float* wr = &Wl[pi*256 + cc*8];
        facc[pi] += wr[0]*h0 + wr[1]*h1 + wr[2]*h2 + wr[3]*h3
                  + wr[4]*h4 + wr[5]*h5 + wr[6]*h6 + wr[7]*h7;
      }
    }
    float y0 = 0.f, y1 = 0.f;
    #pragma unroll
    for (int pi = 0; pi < 32; ++pi) {
      int p = pi >> 4, i = pi & 15;
      float xv = (float)Xh[((size_t)(b*16 + i)*TP + t)*136 + p*68 + 64];
      if (p == 0) y0 += facc[pi]*xv; else y1 += facc[pi]*xv;
    }
    Yh[((size_t)(b*16 + o)*NFR + t)*136 + 0*68 + 64] = (h16)y0;
    Yh[((size_t)(b*16 + o)*NFR + t)*136 + 1*68 + 64] = (h16)y1;
  }
}

// iSTFT: MFMA fr = Tist[128k x 136c] * Yl[136c x t], OLA in LDS, invden in table
__launch_bounds__(256)
__global__ void dfc_istft(const u16* __restrict__ Y16, const float* __restrict__ wsp,
                          const float* __restrict__ bias, float* __restrict__ out) {
  __shared__ __align__(16) char YL[80*336];
  const int u = blockIdx.x, row = blockIdx.y, tid = threadIdx.x;
  const int wave = tid >> 6, lane = tid & 63;
  const int l15 = lane & 15, g16 = lane >> 4;
  for (int i = tid; i < 1680; i += 256) ((float4*)YL)[i] = float4{0.f,0.f,0.f,0.f};
  __syncthreads();
  const char* Yb = (const char*)Y16 + ((size_t)row*NFR + u*64)*272;
  for (int ch = tid; ch < 1105; ch += 256) {
    int tl = ch / 17, cc = ch - tl*17;
    float4 v = F4(Yb + (size_t)tl*272 + cc*16);
    *(float4*)(YL + tl*336 + cc*16) = v;
  }
  __syncthreads();
  const h16* Ti = (const h16*)(wsp + OFF_TI);
  f32x4 acc[2][5] = {};
  #pragma unroll
  for (int ks = 0; ks < 5; ++ks) {
    half8 Af[2];
    #pragma unroll
    for (int m = 0; m < 2; ++m)
      Af[m] = *(const half8*)(Ti + (size_t)((wave*2 + m)*16 + l15)*160 + ks*32 + g16*8);
    #pragma unroll
    for (int nt = 0; nt < 5; ++nt) {
      half8 Bf = *(const half8*)(YL + (nt*16 + l15)*336 + ks*64 + g16*16);
      acc[0][nt] = __builtin_amdgcn_mfma_f32_16x16x32_f16(Af[0], Bf, acc[0][nt], 0,0,0);
      acc[1][nt] = __builtin_amdgcn_mfma_f32_16x16x32_f16(Af[1], Bf, acc[1][nt], 0,0,0);
    }
  }
  __syncthreads();
  float* outT = (float*)YL;
  if (wave >= 2) {
    #pragma unroll
    for (int m = 0; m < 2; ++m) {
      int j0 = (wave*2 + m - 4)*16 + g16*4;
      #pragma unroll
      for (int nt = 0; nt < 4; ++nt) {
        int t = nt*16 + l15;
        *(f32x4*)&outT[t*68 + j0] = acc[m][nt];
      }
    }
  }
  __syncthreads();
  if (wave < 2) {
    #pragma unroll
    for (int m = 0; m < 2; ++m) {
      int j0 = (wave*2 + m)*16 + g16*4;
      #pragma unroll
      for (int nt = 0; nt < 5; ++nt) {
        int t = nt*16 + l15;
        if (t >= 1 && t <= 64) {
          f32x4 v = *(f32x4*)&outT[(t-1)*68 + j0];
          v[0] += acc[m][nt][0]; v[1] += acc[m][nt][1];
          v[2] += acc[m][nt][2]; v[3] += acc[m][nt][3];
          *(f32x4*)&outT[(t-1)*68 + j0] = v;
        }
      }
    }
  }
  __syncthreads();
  const float bv = bias[row & 15];
  float* og = out + (size_t)row*TLEN + (size_t)u*4096;
  #pragma unroll
  for (int r = 0; r < 4; ++r) {
    int fi = tid + 256*r;
    int sg = fi >> 4, jj = (fi & 15)*4;
    float4 v = *(float4*)&outT[sg*68 + jj];
    float4 w{v.x + bv, v.y + bv, v.z + bv, v.w + bv};
    *(float4*)(og + sg*64 + jj) = w;
  }
}

extern "C" void kernel_launch(void* const* d_in, const int* in_sizes, int n_in,
                              void* d_out, int out_size, void* d_ws, size_t ws_size,
                              hipStream_t stream) {
  (void)in_sizes; (void)n_in; (void)out_size; (void)ws_size;
  const float* x    = (const float*)d_in[0];
  const float* cond = (const float*)d_in[1];
  const float* w1   = (const float*)d_in[2];
  const float* b1   = (const float*)d_in[3];
  const float* w2   = (const float*)d_in[4];
  const float* b2   = (const float*)d_in[5];
  const float* bias = (const float*)d_in[6];
  float* ws  = (float*)d_ws;
  float* out = (float*)d_out;
  u16* R     = (u16*)(ws + OFF_R);      // hpart then w216
  u16* b2p   = (u16*)(ws + OFF_B2P);
  u16* hT16  = (u16*)(ws + OFF_HT);
  u16* X16   = (u16*)(ws + OFF_X16);
  u16* Y16   = (u16*)(ws + OFF_Y16);
  u16* w116  = (u16*)(ws + OFF_W116);

  (void)hipMemsetAsync(hT16, 0, (size_t)8*TP*256*2, stream);
  (void)hipMemsetAsync(X16, 0, (size_t)128*TP*136*2, stream);
  dfc_tables<<<dim3(1), dim3(256), 0, stream>>>(ws);
  dfc_prep_w1<<<dim3(2048), dim3(256), 0, stream>>>(w1, w116);
  dfc_conv1<<<dim3(9, 8, 8), dim3(512), 100352, stream>>>(cond, w116, R);
  dfc_hred<<<dim3(513), dim3(256), 0, stream>>>(R, b1, hT16);
  dfc_prep_w2<<<dim3(4160), dim3(256), 0, stream>>>(w2, R);
  dfc_prep_b2<<<dim3(128), dim3(256), 0, stream>>>(b2, b2p);
  dfc_stft<<<dim3(6, 128), dim3(256), 0, stream>>>(x, ws, X16);
  dfc_conv2y<<<dim3(6, 16, 8), dim3(256), 0, stream>>>(R, hT16, b2p, X16, Y16);
  dfc_edge<<<dim3(16, 8, 2), dim3(256), 0, stream>>>(w2, b2, hT16, X16, Y16);
  dfc_istft<<<dim3(8, 128), dim3(256), 0, stream>>>(Y16, ws, bias, out);
}